// Round 13
// baseline (263.319 us; speedup 1.0000x reference)
//
#include <hip/hip_runtime.h>
#include <hip/hip_bf16.h>
#include <hip/hip_fp8.h>

typedef __attribute__((ext_vector_type(8))) short bf16x8;
typedef __attribute__((ext_vector_type(4))) float f32x4;
typedef __attribute__((ext_vector_type(2))) float f32x2;

constexpr int NT = 2000, NW = 50000, ND = 20000;
constexpr float INV_SQRT_DK = 0.17677669529663687f;  // 1/sqrt(32)

__device__ inline float bfu(unsigned short u) {
    return __uint_as_float(((unsigned int)u) << 16);
}
__device__ inline float blo(unsigned int u) { return __uint_as_float(u << 16); }
__device__ inline float bhi(unsigned int u) { return __uint_as_float(u & 0xffff0000u); }
__device__ inline short f2bf(float x) {
    __hip_bfloat16 h = __float2bfloat16(x);
    short s; __builtin_memcpy(&s, &h, 2); return s;
}

// ---- fp8 e4m3 (OCP) helpers: HW cvt with SW fallback ----
__device__ inline void dec4(unsigned int w, float* o) {
#if __has_builtin(__builtin_amdgcn_cvt_pk_f32_fp8)
    f32x2 a = __builtin_amdgcn_cvt_pk_f32_fp8(w, false);
    f32x2 b = __builtin_amdgcn_cvt_pk_f32_fp8(w, true);
    o[0] = a[0]; o[1] = a[1]; o[2] = b[0]; o[3] = b[1];
#else
    __hip_fp8_e4m3 t0, t1, t2, t3;
    t0.__x = (__hip_fp8_storage_t)(w & 0xff);
    t1.__x = (__hip_fp8_storage_t)((w >> 8) & 0xff);
    t2.__x = (__hip_fp8_storage_t)((w >> 16) & 0xff);
    t3.__x = (__hip_fp8_storage_t)((w >> 24) & 0xff);
    o[0] = (float)t0; o[1] = (float)t1; o[2] = (float)t2; o[3] = (float)t3;
#endif
}
__device__ inline unsigned char f2fp8(float v) {
#if __has_builtin(__builtin_amdgcn_cvt_pk_fp8_f32)
    return (unsigned char)(__builtin_amdgcn_cvt_pk_fp8_f32(v, v, 0u, false) & 0xff);
#else
    __hip_fp8_e4m3 h(v); return (unsigned char)h.__x;
#endif
}

// scalar stores (r9 epilogue)
__device__ inline void cstore(float* p, float v) { *p = v; }
__device__ inline void cstore(short* p, float v) { *p = f2bf(v); }
__device__ inline void cstore(unsigned char* p, float v) { *p = f2fp8(v); }

// packed 4-consecutive-column stores (swapped-operand epilogue)
__device__ inline void cstore4(float* p, float4 v) {
    *reinterpret_cast<float4*>(p) = v;
}
__device__ inline void cstore4(short* p, float4 v) {
    short4 s; s.x = f2bf(v.x); s.y = f2bf(v.y); s.z = f2bf(v.z); s.w = f2bf(v.w);
    *reinterpret_cast<short4*>(p) = s;
}
__device__ inline void cstore4(unsigned char* p, float4 v) {
#if __has_builtin(__builtin_amdgcn_cvt_pk_fp8_f32)
    unsigned int w = __builtin_amdgcn_cvt_pk_fp8_f32(v.x, v.y, 0u, false);
    w = __builtin_amdgcn_cvt_pk_fp8_f32(v.z, v.w, w, true);
    *reinterpret_cast<unsigned int*>(p) = w;
#else
    p[0] = f2fp8(v.x); p[1] = f2fp8(v.y); p[2] = f2fp8(v.z); p[3] = f2fp8(v.w);
#endif
}

__device__ inline void gload16(const short* g, short* l) {
    __builtin_amdgcn_global_load_lds(
        (const __attribute__((address_space(1))) void*)g,
        (__attribute__((address_space(3))) void*)l, 16, 0, 0);
}

// 32-element fp8 dot against fp32 q in registers
__device__ inline float dot32f8(const unsigned char* __restrict__ kp, const float* __restrict__ qh) {
    const uint4 u = *reinterpret_cast<const uint4*>(kp);
    const uint4 v = *reinterpret_cast<const uint4*>(kp + 16);
    const unsigned int ws[8] = {u.x, u.y, u.z, u.w, v.x, v.y, v.z, v.w};
    float d = 0.f;
    #pragma unroll
    for (int c = 0; c < 8; ++c) {
        float f[4];
        dec4(ws[c], f);
        d += qh[c * 4 + 0] * f[0] + qh[c * 4 + 1] * f[1]
           + qh[c * 4 + 2] * f[2] + qh[c * 4 + 3] * f[3];
    }
    return d;
}

// =====================================================================
// fp32 -> bf16 convert (vectorized, grid-stride); n8 = count/8
// =====================================================================
__global__ __launch_bounds__(256) void cvt_bf16(
    const float* __restrict__ src, short* __restrict__ dst, int n8)
{
    const int stride = gridDim.x * 256;
    for (int i = blockIdx.x * 256 + threadIdx.x; i < n8; i += stride) {
        const float* p = src + (long)i * 8;
        const float4 x0 = *reinterpret_cast<const float4*>(p);
        const float4 x1 = *reinterpret_cast<const float4*>(p + 4);
        bf16x8 v;
        v[0] = f2bf(x0.x); v[1] = f2bf(x0.y); v[2] = f2bf(x0.z); v[3] = f2bf(x0.w);
        v[4] = f2bf(x1.x); v[5] = f2bf(x1.y); v[6] = f2bf(x1.z); v[7] = f2bf(x1.w);
        *reinterpret_cast<bf16x8*>(dst + (long)i * 8) = v;
    }
}

// =====================================================================
// fold: per-relation head transforms folded into projection weights,
// written TRANSPOSED bf16 ([n][k]) into the packed B matrices.
// =====================================================================
__global__ __launch_bounds__(256) void fold_kernel(
    const float* __restrict__ Wk, const float* __restrict__ bk,
    const float* __restrict__ Wv, const float* __restrict__ bv,
    const float* __restrict__ rel_att, const float* __restrict__ rel_msg,
    short* __restrict__ B_t1, short* __restrict__ B_w, short* __restrict__ B_t2,
    float* __restrict__ bias_t1, float* __restrict__ bias_w, float* __restrict__ bias_t2)
{
    const int f = blockIdx.x >> 3, chunk = blockIdx.x & 7;
    const int rel = f >> 1, isV = f & 1;
    const int ntype = (rel == 1 || rel == 3) ? 1 : 0;
    const float* Wsrc = (isV ? Wv : Wk) + ntype * 65536;
    const float* bsrc = (isV ? bv : bk) + ntype * 256;
    const float* A    = (isV ? rel_msg : rel_att) + rel * 8192;  // [8][32][32]
    short* wdst; float* bdst;
    switch (f) {
        case 0: wdst = B_t1 + 65536;     bdst = bias_t1 + 256; break;  // K tt
        case 1: wdst = B_t1 + 2 * 65536; bdst = bias_t1 + 512; break;  // V tt
        case 2: wdst = B_w;              bdst = bias_w;        break;  // K wt
        case 3: wdst = B_w + 65536;      bdst = bias_w + 256;  break;  // V wt
        case 4: wdst = B_t2;             bdst = bias_t2;       break;  // K td
        case 5: wdst = B_t2 + 65536;     bdst = bias_t2 + 256; break;  // V td
        case 6: wdst = B_w + 2 * 65536;  bdst = bias_w + 512;  break;  // K wd
        default: wdst = B_w + 3 * 65536; bdst = bias_w + 768;  break;  // V wd
    }
    __shared__ float Wsh[32][256];
    const int tid = threadIdx.x;
    for (int i = 0; i < 32; ++i)
        Wsh[i][tid] = Wsrc[(chunk * 32 + i) * 256 + tid];
    __syncthreads();
    const int h = tid >> 5, o = tid & 31;
    float a[32];
    #pragma unroll
    for (int d = 0; d < 32; ++d) a[d] = A[h * 1024 + d * 32 + o];
    short tmp[32];
    #pragma unroll
    for (int r = 0; r < 32; ++r) {
        float s = 0.f;
        #pragma unroll
        for (int d = 0; d < 32; ++d) s = fmaf(Wsh[r][(h << 5) + d], a[d], s);
        tmp[r] = f2bf(s);
    }
    short* wp = wdst + tid * 256 + chunk * 32;
    #pragma unroll
    for (int r8 = 0; r8 < 4; ++r8) {
        bf16x8 v;
        #pragma unroll
        for (int t = 0; t < 8; ++t) v[t] = tmp[r8 * 8 + t];
        *reinterpret_cast<bf16x8*>(wp + r8 * 8) = v;
    }
    if (chunk == 0) {
        float s = 0.f;
        #pragma unroll
        for (int d = 0; d < 32; ++d) s = fmaf(bsrc[(h << 5) + d], a[d], s);
        bdst[tid] = s;
    }
}

struct TransP { const float* s[6]; short* d[6]; };
__global__ __launch_bounds__(256) void wtrans6(TransP p) {
    const int m = blockIdx.y, n = blockIdx.x, k = threadIdx.x;
    p.d[m][n * 256 + k] = f2bf(p.s[m][k * 256 + n]);
}

__global__ void copy_bias(const float* __restrict__ s, float* __restrict__ d) {
    d[threadIdx.x] = s[threadIdx.x];
}

// =====================================================================
// Packed epilogue (swapped-operand MFMA: thread owns 4 consecutive cols)
// =====================================================================
template <typename OutT, int EPI, int NI>
__device__ inline void epilogue(
    f32x4 (&acc)[NI][4], const float* __restrict__ bias, OutT* __restrict__ C,
    int M, int ldc, const float* __restrict__ extra,
    const float* __restrict__ skipv, int skipIdx,
    int row0, int col0, int wm, int wn, int r, int kb)
{
    float alpha = 0.f;
    if (EPI == 1) alpha = 1.f / (1.f + __expf(-skipv[skipIdx]));
    float4 b4[4];
    #pragma unroll
    for (int j = 0; j < 4; ++j)
        b4[j] = *reinterpret_cast<const float4*>(&bias[col0 + wn * 64 + j * 16 + kb * 4]);
    #pragma unroll
    for (int i = 0; i < NI; ++i) {
        const int rrow = row0 + wm * 64 + i * 16 + r;
        if (rrow >= M) continue;
        #pragma unroll
        for (int j = 0; j < 4; ++j) {
            const int cb = col0 + wn * 64 + j * 16 + kb * 4;
            float4 v;
            v.x = acc[i][j][0] + b4[j].x;
            v.y = acc[i][j][1] + b4[j].y;
            v.z = acc[i][j][2] + b4[j].z;
            v.w = acc[i][j][3] + b4[j].w;
            if (EPI == 1) {
                const float4 e = *reinterpret_cast<const float4*>(&extra[rrow * 256 + cb]);
                v.x = alpha * v.x + (1.f - alpha) * e.x;
                v.y = alpha * v.y + (1.f - alpha) * e.y;
                v.z = alpha * v.z + (1.f - alpha) * e.z;
                v.w = alpha * v.w + (1.f - alpha) * e.w;
            }
            if (EPI == 2) {
                const float4 e = *reinterpret_cast<const float4*>(&extra[rrow * 256 + cb]);
                v.x = tanhf(v.x + e.x);
                v.y = tanhf(v.y + e.y);
                v.z = tanhf(v.z + e.z);
                v.w = tanhf(v.w + e.w);
            }
            cstore4(C + rrow * ldc + cb, v);
        }
    }
}

// =====================================================================
// LDS-staged MFMA GEMM, 256 threads, 128x128 tile, BK=64, single-buffered,
// conflict-free XOR swizzle. Swapped MFMA + packed epilogue.
// =====================================================================
template <bool XF32, typename OutT, int EPI, bool SWZ>
__global__ __launch_bounds__(256) void gemm_lds(
    const void* __restrict__ Xv, const short* __restrict__ Wt,
    const float* __restrict__ bias, OutT* __restrict__ C,
    int M, int ldc, const float* __restrict__ extra,
    const float* __restrict__ skipv, int skipIdx)
{
    __shared__ short As[128 * 64];
    __shared__ short Bs[128 * 64];
    int bxi = blockIdx.x, byi = blockIdx.y;
    if constexpr (SWZ) {
        const int h = bxi + (int)gridDim.x * byi;
        const int i = h >> 3;
        byi = (h & 7) + 8 * (i >> 3);
        bxi = i & 7;
        if (byi * 128 >= M) return;
    }
    const int tid = threadIdx.x;
    const int wave = tid >> 6, lane = tid & 63;
    const int wm = wave >> 1, wn = wave & 1;
    const int r = lane & 15, kb = lane >> 4;
    const int col0 = bxi * 128;
    const int row0 = byi * 128;

    const int l8 = lane >> 3;
    const int c8 = lane & 7;
    const int swz8 = c8 ^ l8;
    f32x4 acc[4][4] = {};

    for (int k0 = 0; k0 < 256; k0 += 64) {
        if (k0) __syncthreads();
        if constexpr (XF32) {
            #pragma unroll
            for (int q = 0; q < 4; ++q) {
                const int rl = wave * 32 + q * 8 + l8;
                const int grow = min(row0 + rl, M - 1);
                const float* xp = (const float*)Xv + grow * 256 + k0 + c8 * 8;
                const float4 x0 = *reinterpret_cast<const float4*>(xp);
                const float4 x1 = *reinterpret_cast<const float4*>(xp + 4);
                bf16x8 v;
                v[0] = f2bf(x0.x); v[1] = f2bf(x0.y); v[2] = f2bf(x0.z); v[3] = f2bf(x0.w);
                v[4] = f2bf(x1.x); v[5] = f2bf(x1.y); v[6] = f2bf(x1.z); v[7] = f2bf(x1.w);
                *reinterpret_cast<bf16x8*>(As + rl * 64 + swz8 * 8) = v;
            }
        } else {
            #pragma unroll
            for (int q = 0; q < 4; ++q) {
                const int rl = wave * 32 + q * 8 + l8;
                const int grow = min(row0 + rl, M - 1);
                gload16((const short*)Xv + grow * 256 + k0 + swz8 * 8,
                        As + (wave * 32 + q * 8) * 64);
            }
        }
        #pragma unroll
        for (int q = 0; q < 4; ++q) {
            const int cl = wave * 32 + q * 8 + l8;
            gload16(Wt + (col0 + cl) * 256 + k0 + swz8 * 8,
                    Bs + (wave * 32 + q * 8) * 64);
        }
        __syncthreads();
        #pragma unroll
        for (int s = 0; s < 2; ++s) {
            const int csw = ((kb + 4 * s) ^ (r & 7)) * 8;
            bf16x8 af[4], bw[4];
            #pragma unroll
            for (int i = 0; i < 4; ++i) {
                af[i] = *reinterpret_cast<const bf16x8*>(As + (wm * 64 + i * 16 + r) * 64 + csw);
                bw[i] = *reinterpret_cast<const bf16x8*>(Bs + (wn * 64 + i * 16 + r) * 64 + csw);
            }
            #pragma unroll
            for (int i = 0; i < 4; ++i)
                #pragma unroll
                for (int j = 0; j < 4; ++j)
                    acc[i][j] = __builtin_amdgcn_mfma_f32_16x16x32_bf16(bw[j], af[i], acc[i][j], 0, 0, 0);
        }
    }
    epilogue<OutT, EPI, 4>(acc, bias, C, M, ldc, extra, skipv, skipIdx,
                           row0, col0, wm, wn, r, kb);
}

// =====================================================================
// Dual-output phase-1 topic projection: A=feat_topic (fp32), B=B_t1
// (768 cols packed: 0-255 -> q_t bf16 ldc=256, 256-767 -> kv1 fp8 ldc=512).
// =====================================================================
__global__ __launch_bounds__(256) void gemm_qkv(
    const float* __restrict__ X, const short* __restrict__ Wt,
    const float* __restrict__ bias, short* __restrict__ Qo,
    unsigned char* __restrict__ KVo, int M)
{
    __shared__ short As[128 * 64];
    __shared__ short Bs[128 * 64];
    const int bxi = blockIdx.x, byi = blockIdx.y;
    const int tid = threadIdx.x;
    const int wave = tid >> 6, lane = tid & 63;
    const int wm = wave >> 1, wn = wave & 1;
    const int r = lane & 15, kb = lane >> 4;
    const int col0 = bxi * 128;
    const int row0 = byi * 128;

    const int l8 = lane >> 3;
    const int c8 = lane & 7;
    const int swz8 = c8 ^ l8;
    f32x4 acc[4][4] = {};

    for (int k0 = 0; k0 < 256; k0 += 64) {
        if (k0) __syncthreads();
        #pragma unroll
        for (int q = 0; q < 4; ++q) {
            const int rl = wave * 32 + q * 8 + l8;
            const int grow = min(row0 + rl, M - 1);
            const float* xp = X + grow * 256 + k0 + c8 * 8;
            const float4 x0 = *reinterpret_cast<const float4*>(xp);
            const float4 x1 = *reinterpret_cast<const float4*>(xp + 4);
            bf16x8 v;
            v[0] = f2bf(x0.x); v[1] = f2bf(x0.y); v[2] = f2bf(x0.z); v[3] = f2bf(x0.w);
            v[4] = f2bf(x1.x); v[5] = f2bf(x1.y); v[6] = f2bf(x1.z); v[7] = f2bf(x1.w);
            *reinterpret_cast<bf16x8*>(As + rl * 64 + swz8 * 8) = v;
        }
        #pragma unroll
        for (int q = 0; q < 4; ++q) {
            const int cl = wave * 32 + q * 8 + l8;
            gload16(Wt + (col0 + cl) * 256 + k0 + swz8 * 8,
                    Bs + (wave * 32 + q * 8) * 64);
        }
        __syncthreads();
        #pragma unroll
        for (int s = 0; s < 2; ++s) {
            const int csw = ((kb + 4 * s) ^ (r & 7)) * 8;
            bf16x8 af[4], bw[4];
            #pragma unroll
            for (int i = 0; i < 4; ++i) {
                af[i] = *reinterpret_cast<const bf16x8*>(As + (wm * 64 + i * 16 + r) * 64 + csw);
                bw[i] = *reinterpret_cast<const bf16x8*>(Bs + (wn * 64 + i * 16 + r) * 64 + csw);
            }
            #pragma unroll
            for (int i = 0; i < 4; ++i)
                #pragma unroll
                for (int j = 0; j < 4; ++j)
                    acc[i][j] = __builtin_amdgcn_mfma_f32_16x16x32_bf16(bw[j], af[i], acc[i][j], 0, 0, 0);
        }
    }

    float4 b4[4];
    #pragma unroll
    for (int j = 0; j < 4; ++j)
        b4[j] = *reinterpret_cast<const float4*>(&bias[col0 + wn * 64 + j * 16 + kb * 4]);
    #pragma unroll
    for (int i = 0; i < 4; ++i) {
        const int rrow = row0 + wm * 64 + i * 16 + r;
        if (rrow >= M) continue;
        #pragma unroll
        for (int j = 0; j < 4; ++j) {
            const int cb = col0 + wn * 64 + j * 16 + kb * 4;
            float4 v;
            v.x = acc[i][j][0] + b4[j].x;
            v.y = acc[i][j][1] + b4[j].y;
            v.z = acc[i][j][2] + b4[j].z;
            v.w = acc[i][j][3] + b4[j].w;
            if (bxi < 2) cstore4(Qo + rrow * 256 + cb, v);
            else         cstore4(KVo + rrow * 512 + (cb - 256), v);
        }
    }
}

// =====================================================================
// Big-tile GEMM: 512 threads (8 waves 4x2), 256x128 tile, BK=64,
// single-buffered, same swizzle. SWAP selects packed epilogue (true)
// or r9-exact unswapped path (false; proven for word GEMM).
// =====================================================================
template <bool XF32, typename OutT, int EPI, bool SWZ, bool SWAP>
__global__ __launch_bounds__(512) void gemm_w(
    const void* __restrict__ Xv, const short* __restrict__ Wt,
    const float* __restrict__ bias, OutT* __restrict__ C,
    int M, int ldc, const float* __restrict__ extra,
    const float* __restrict__ skipv, int skipIdx)
{
    __shared__ short As[256 * 64];   // 32 KB
    __shared__ short Bs[128 * 64];   // 16 KB
    int bxi = blockIdx.x, byi = blockIdx.y;
    if constexpr (SWZ) {
        const int h = bxi + (int)gridDim.x * byi;
        const int i = h >> 3;
        byi = (h & 7) + 8 * (i >> 3);
        bxi = i & 7;
        if (byi * 256 >= M) return;
    }
    const int tid = threadIdx.x;
    const int wave = tid >> 6, lane = tid & 63;
    const int wm = wave >> 1, wn = wave & 1;      // 4x2 wave grid
    const int r = lane & 15, kb = lane >> 4;
    const int col0 = bxi * 128;
    const int row0 = byi * 256;

    const int l8 = lane >> 3;
    const int c8 = lane & 7;
    const int swz8 = c8 ^ l8;
    f32x4 acc[4][4] = {};

    for (int k0 = 0; k0 < 256; k0 += 64) {
        if (k0) __syncthreads();
        if constexpr (XF32) {
            #pragma unroll
            for (int q = 0; q < 4; ++q) {
                const int rl = wave * 32 + q * 8 + l8;
                const int grow = min(row0 + rl, M - 1);
                const float* xp = (const float*)Xv + grow * 256 + k0 + c8 * 8;
                const float4 x0 = *reinterpret_cast<const float4*>(xp);
                const float4 x1 = *reinterpret_cast<const float4*>(xp + 4);
                bf16x8 v;
                v[0] = f2bf(x0.x); v[1] = f2bf(x0.y); v[2] = f2bf(x0.z); v[3] = f2bf(x0.w);
                v[4] = f2bf(x1.x); v[5] = f2bf(x1.y); v[6] = f2bf(x1.z); v[7] = f2bf(x1.w);
                *reinterpret_cast<bf16x8*>(As + rl * 64 + swz8 * 8) = v;
            }
        } else {
            #pragma unroll
            for (int q = 0; q < 4; ++q) {
                const int rl = wave * 32 + q * 8 + l8;
                const int grow = min(row0 + rl, M - 1);
                gload16((const short*)Xv + grow * 256 + k0 + swz8 * 8,
                        As + (wave * 32 + q * 8) * 64);
            }
        }
        #pragma unroll
        for (int q = 0; q < 2; ++q) {
            const int cl = wave * 16 + q * 8 + l8;
            gload16(Wt + (col0 + cl) * 256 + k0 + swz8 * 8,
                    Bs + (wave * 16 + q * 8) * 64);
        }
        __syncthreads();
        #pragma unroll
        for (int s = 0; s < 2; ++s) {
            const int csw = ((kb + 4 * s) ^ (r & 7)) * 8;
            bf16x8 af[4], bw[4];
            #pragma unroll
            for (int i = 0; i < 4; ++i) {
                af[i] = *reinterpret_cast<const bf16x8*>(As + (wm * 64 + i * 16 + r) * 64 + csw);
                bw[i] = *reinterpret_cast<const bf16x8*>(Bs + (wn * 64 + i * 16 + r) * 64 + csw);
            }
            #pragma unroll
            for (int i = 0; i < 4; ++i)
                #pragma unroll
                for (int j = 0; j < 4; ++j) {
                    if constexpr (SWAP)
                        acc[i][j] = __builtin_amdgcn_mfma_f32_16x16x32_bf16(bw[j], af[i], acc[i][j], 0, 0, 0);
                    else
                        acc[i][j] = __builtin_amdgcn_mfma_f32_16x16x32_bf16(af[i], bw[j], acc[i][j], 0, 0, 0);
                }
        }
    }

    if constexpr (SWAP) {
        epilogue<OutT, EPI, 4>(acc, bias, C, M, ldc, extra, skipv, skipIdx,
                               row0, col0, wm, wn, r, kb);
    } else {
        // r9-exact scalar epilogue
        float alpha = 0.f;
        if (EPI == 1) alpha = 1.f / (1.f + __expf(-skipv[skipIdx]));
        #pragma unroll
        for (int i = 0; i < 4; ++i) {
            #pragma unroll
            for (int j = 0; j < 4; ++j) {
                const int col = col0 + wn * 64 + j * 16 + r;
                const float bc = bias[col];
                #pragma unroll
                for (int t = 0; t < 4; ++t) {
                    const int rrow = row0 + wm * 64 + i * 16 + kb * 4 + t;
                    if (rrow < M) {
                        float v = acc[i][j][t] + bc;
                        if (EPI == 1) v = alpha * v + (1.f - alpha) * extra[rrow * 256 + col];
                        if (EPI == 2) v = tanhf(v + extra[rrow * 256 + col]);
                        cstore(C + rrow * ldc + col, v);
                    }
                }
            }
        }
    }
}

// =====================================================================
// msg_k: both relations fp8 K/V. Per-head 32-lane score groups with
// q hoisted to registers; register softmax (pre-divided); 8-slot
// accumulate with 8B fp8 loads; swizzled LDS partial-sum reduce.
// =====================================================================
template <int NE>
__device__ inline void rel_scores_f8(const unsigned char* __restrict__ kv, int ld, int koff,
                                     const int* __restrict__ sidx, int off, float scale,
                                     const float* __restrict__ qh, float* __restrict__ sc,
                                     int g, int l)
{
    constexpr int NL = NE / 32;
    float att[NL];
    #pragma unroll
    for (int t = 0; t < NL; ++t)
        att[t] = dot32f8(kv + (size_t)sidx[off + l + 32 * t] * ld + koff + g * 32, qh) * scale;
    float m = att[0];
    #pragma unroll
    for (int t = 1; t < NL; ++t) m = fmaxf(m, att[t]);
    #pragma unroll
    for (int o = 16; o > 0; o >>= 1) m = fmaxf(m, __shfl_xor(m, o));
    float ex[NL], s = 0.f;
    #pragma unroll
    for (int t = 0; t < NL; ++t) { ex[t] = __expf(att[t] - m); s += ex[t]; }
    #pragma unroll
    for (int o = 16; o > 0; o >>= 1) s += __shfl_xor(s, o);
    const float inv = 1.f / s;
    #pragma unroll
    for (int t = 0; t < NL; ++t) sc[(off + l + 32 * t) * 9 + g] = ex[t] * inv;
}

template <int NE>
__device__ inline void accum_f8(const unsigned char* __restrict__ kv, int ld, int voff,
                                const int* __restrict__ sidx, int off,
                                const float* __restrict__ sc,
                                int es, int ct, int h, float* __restrict__ acc)
{
    #pragma unroll
    for (int e = es; e < NE; e += 8) {
        const float w = sc[(off + e) * 9 + h];
        const uint2 u = *reinterpret_cast<const uint2*>(
            kv + (size_t)sidx[off + e] * ld + voff + ct * 8);
        float f[8];
        dec4(u.x, f); dec4(u.y, f + 4);
        #pragma unroll
        for (int k = 0; k < 8; ++k) acc[k] = fmaf(w, f[k], acc[k]);
    }
}

template <int NEA, int NEB>
__global__ __launch_bounds__(256) void msg_k(
    const short* __restrict__ q, int ldq,
    const unsigned char* __restrict__ kvA, int ldA, int koffA, int voffA,
    const int* __restrict__ srcA,
    const unsigned char* __restrict__ kvB, int ldB, int koffB, int voffB,
    const int* __restrict__ srcB,
    const float* __restrict__ relPri, int relA, int relB,
    short* __restrict__ out, int n_dst)
{
    constexpr int NET = NEA + NEB;
    const int j = blockIdx.x, tid = threadIdx.x;
    __shared__ float qsh[256];
    __shared__ int sidx[NET];
    __shared__ float sc[NET * 9];
    __shared__ float psA[8][256];
    __shared__ float psB[8][256];

    qsh[tid] = bfu((unsigned short)q[j * ldq + tid]);
    if (tid < NEA) sidx[tid] = srcA[j + tid * n_dst];
    else if (tid < NET) sidx[tid] = srcB[j + (tid - NEA) * n_dst];
    __syncthreads();

    const int g = tid >> 5, l = tid & 31;
    float qr[32];
    #pragma unroll
    for (int c = 0; c < 8; ++c) {
        const float4 v = *reinterpret_cast<const float4*>(qsh + g * 32 + c * 4);
        qr[c * 4] = v.x; qr[c * 4 + 1] = v.y; qr[c * 4 + 2] = v.z; qr[c * 4 + 3] = v.w;
    }

    if constexpr (NEA == 16 && NEB == 16) {
        const int isB = l >> 4;
        const unsigned char* base = isB ? kvB + koffB : kvA + koffA;
        const int ld = isB ? ldB : ldA;
        const float scale = relPri[(isB ? relB : relA) * 8 + g] * INV_SQRT_DK;
        const float att = dot32f8(base + (size_t)sidx[l] * ld + g * 32, qr) * scale;
        float m = att;
        #pragma unroll
        for (int o = 8; o > 0; o >>= 1) m = fmaxf(m, __shfl_xor(m, o));
        const float ex = __expf(att - m);
        float s = ex;
        #pragma unroll
        for (int o = 8; o > 0; o >>= 1) s += __shfl_xor(s, o);
        sc[l * 9 + g] = ex / s;
    } else {
        rel_scores_f8<NEA>(kvA, ldA, koffA, sidx, 0,
                           relPri[relA * 8 + g] * INV_SQRT_DK, qr, sc, g, l);
        rel_scores_f8<NEB>(kvB, ldB, koffB, sidx, NEA,
                           relPri[relB * 8 + g] * INV_SQRT_DK, qr, sc, g, l);
    }
    __syncthreads();

    const int es = tid >> 5, ct = tid & 31, hh = ct >> 2;
    float accA[8] = {}, accB[8] = {};
    accum_f8<NEA>(kvA, ldA, voffA, sidx, 0,   sc, es, ct, hh, accA);
    accum_f8<NEB>(kvB, ldB, voffB, sidx, NEA, sc, es, ct, hh, accB);
    const int sw = ct & 4;
    *reinterpret_cast<float4*>(&psA[es][(ct * 8) ^ sw])     = make_float4(accA[0], accA[1], accA[2], accA[3]);
    *reinterpret_cast<float4*>(&psA[es][(ct * 8 + 4) ^ sw]) = make_float4(accA[4], accA[5], accA[6], accA[7]);
    *reinterpret_cast<float4*>(&psB[es][(ct * 8) ^ sw])     = make_float4(accB[0], accB[1], accB[2], accB[3]);
    *reinterpret_cast<float4*>(&psB[es][(ct * 8 + 4) ^ sw]) = make_float4(accB[4], accB[5], accB[6], accB[7]);
    __syncthreads();

    float rA = 0.f, rB = 0.f;
    const int rp = tid ^ ((tid >> 3) & 4);
    #pragma unroll
    for (int e2 = 0; e2 < 8; ++e2) { rA += psA[e2][rp]; rB += psB[e2][rp]; }
    out[j * 256 + tid] = f2bf(0.5f * (fmaxf(rA, 0.f) + fmaxf(rB, 0.f)));
}

// =====================================================================
template <bool WB>
__global__ __launch_bounds__(256) void ln_k(
    float* __restrict__ data, const float* __restrict__ g,
    const float* __restrict__ b, int nrows, short* __restrict__ bfout)
{
    const int wid = threadIdx.x >> 6, lane = threadIdx.x & 63;
    const int row = blockIdx.x * 4 + wid;
    if (row >= nrows) return;
    float4 x = *reinterpret_cast<float4*>(data + row * 256 + lane * 4);
    float s  = x.x + x.y + x.z + x.w;
    float q2 = x.x * x.x + x.y * x.y + x.z * x.z + x.w * x.w;
    #pragma unroll
    for (int o = 32; o > 0; o >>= 1) { s += __shfl_xor(s, o); q2 += __shfl_xor(q2, o); }
    const float mu  = s * (1.f / 256.f);
    const float var = q2 * (1.f / 256.f) - mu * mu;
    const float rr = rsqrtf(var + 1e-5f);
    const float4 gg = *reinterpret_cast<const float4*>(g + lane * 4);
    const float4 bb = *reinterpret_cast<const float4*>(b + lane * 4);
    x.x = (x.x - mu) * rr * gg.x + bb.x;
    x.y = (x.y - mu) * rr * gg.y + bb.y;
    x.z = (x.z - mu) * rr * gg.z + bb.z;
    x.w = (x.w - mu) * rr * gg.w + bb.w;
    *reinterpret_cast<float4*>(data + row * 256 + lane * 4) = x;
    if (WB) {
        ushort4 u;
        u.x = (unsigned short)f2bf(x.x); u.y = (unsigned short)f2bf(x.y);
        u.z = (unsigned short)f2bf(x.z); u.w = (unsigned short)f2bf(x.w);
        *reinterpret_cast<ushort4*>((unsigned short*)bfout + row * 256 + lane * 4) = u;
    }
}

// =====================================================================
extern "C" void kernel_launch(void* const* d_in, const int* in_sizes, int n_in,
                              void* d_out, int out_size, void* d_ws, size_t ws_size,
                              hipStream_t stream)
{
    const float* feat_topic = (const float*)d_in[0];
    const float* feat_word  = (const float*)d_in[1];
    const float* feat_doc   = (const float*)d_in[2];
    const float* ht_prev    = (const float*)d_in[3];
    const float* Wk  = (const float*)d_in[4];
    const float* bk  = (const float*)d_in[5];
    const float* Wq  = (const float*)d_in[6];
    const float* bq  = (const float*)d_in[7];
    const float* Wv  = (const float*)d_in[8];
    const float* bv  = (const float*)d_in[9];
    const float* Wa  = (const float*)d_in[10];
    const float* ba  = (const float*)d_in[11];
    const float* ln_g = (const float*)d_in[12];
    const float* ln_b = (const float*)d_in[13];
    const float* skip = (const float*)d_in[14];
    const float* Wih  = (const float*)d_in[15];
    const float* Whh  = (const float*)d_in[16];
    const float* bih  = (const float*)d_in[17];
    const float* bhh  = (const float*)d_in[18];
    const float* rel_pri = (const float*)d_in[19];
    const float* rel_att = (const float*)d_in[20];
    const float* rel_msg = (const float*)d_in[21];
    const int* src_tt = (const int*)d_in[22];
    const int* src_wt = (const int*)d_in[24];
    const int* src_td = (const int*)d_in[26];
    const int* src_wd = (const int*)d_in[28];

    // ---- workspace layout ----
    short* B_t1 = (short*)d_ws;                 // 768*256
    short* B_w  = B_t1 + 196608;                // 1024*256
    short* B_t2 = B_w + 262144;                 // 512*256
    short* Wq2t = B_t2 + 131072;                // 5 x 256*256
    short* Whht = Wq2t + 65536;
    short* Wa0t = Whht + 65536;
    short* Wiht = Wa0t + 65536;
    short* Wa1t = Wiht + 65536;
    short* q_t  = Wa1t + 65536;                 // bf16 [2000][256]
    unsigned char* kv1 = (unsigned char*)(q_t + 512000);  // fp8 [2000][512]  K_tt|V_tt
    unsigned char* w8  = kv1 + 1024000;                   // fp8 [50000][1024] Kwt|Vwt|Kwd|Vwd
    unsigned char* kv2 = w8 + 51200000;                   // fp8 [2000][512]  K_td|V_td
    short* qd   = (short*)(kv2 + 1024000);      // bf16 [20000][256]
    short* ttop = qd + 5120000;                 // bf16 [2000][256]
    short* mixb = ttop + 512000;                // bf16 [2000][256]
    short* tdoc = mixb + 512000;                // bf16 [20000][256]
    short* xt2  = tdoc + 5120000;               // bf16 [2000][256]
    float* bias_t1 = (float*)(xt2 + 512000);    // 768
    float* bias_w  = bias_t1 + 768;             // 1024
    float* bias_t2 = bias_w + 1024;             // 512
    float* r2      = bias_t2 + 512;             // fp32 [2000][256]
    short* wfb     = (short*)(r2 + 512000);     // bf16 [50000][256] feat_word copy

    float* out_topic = (float*)d_out;
    float* out_doc   = out_topic + NT * 256;

    // ---- prep: convert feat_word to bf16; fold weights ----
    cvt_bf16<<<dim3(2048), 256, 0, stream>>>(feat_word, wfb, NW * 256 / 8);
    fold_kernel<<<dim3(64), 256, 0, stream>>>(Wk, bk, Wv, bv, rel_att, rel_msg,
                                              B_t1, B_w, B_t2, bias_t1, bias_w, bias_t2);
    TransP tp;
    tp.s[0] = Wq;            tp.d[0] = B_t1;   // Wq[topic]
    tp.s[1] = Wq + 131072;   tp.d[1] = Wq2t;   // Wq[doc]
    tp.s[2] = Whh;           tp.d[2] = Whht;
    tp.s[3] = Wih;           tp.d[3] = Wiht;
    tp.s[4] = Wa;            tp.d[4] = Wa0t;
    tp.s[5] = Wa + 65536;    tp.d[5] = Wa1t;
    wtrans6<<<dim3(256, 6), 256, 0, stream>>>(tp);
    copy_bias<<<dim3(1), 256, 0, stream>>>(bq, bias_t1);

    // ---- word GEMM: bf16-A gload_lds path (halved A cache traffic),
    //      r9-exact unswapped big-tile, XCD swizzle, fp8 out ----
    gemm_w<false, unsigned char, 0, true, false><<<dim3(8, 200), 512, 0, stream>>>(
        wfb, B_w, bias_w, w8, NW, 1024, nullptr, nullptr, 0);

    // ---- phase-1 topic projections fused (q_t + kv1) ----
    gemm_qkv<<<dim3(6, 16), 256, 0, stream>>>(
        feat_topic, B_t1, bias_t1, q_t, kv1, NT);
    gemm_w<true, short, 0, false, true><<<dim3(2, 79), 512, 0, stream>>>(
        feat_doc, Wq2t, bq + 512, qd, ND, 256, nullptr, nullptr, 0);
    gemm_lds<true, float, 0, false><<<dim3(2, 16), 256, 0, stream>>>(
        ht_prev, Whht, bhh, r2, NT, 256, nullptr, nullptr, 0);

    // ---- messages into topic (tt:64/dst, wt:128/dst, both fp8) ----
    msg_k<64, 128><<<dim3(NT), 256, 0, stream>>>(
        q_t, 256,
        kv1, 512, 0, 256, src_tt,
        w8, 1024, 0, 256, src_wt,
        rel_pri, 0, 1, ttop, NT);

    // ---- topic update: mix -> RNN tanh -> LN ----
    gemm_lds<false, short, 1, false><<<dim3(2, 16), 256, 0, stream>>>(
        ttop, Wa0t, ba, mixb, NT, 256, feat_topic, skip, 0);
    gemm_lds<false, float, 2, false><<<dim3(2, 16), 256, 0, stream>>>(
        mixb, Wiht, bih, out_topic, NT, 256, r2, nullptr, 0);
    ln_k<true><<<dim3(500), 256, 0, stream>>>(out_topic, ln_g, ln_b, NT, xt2);

    // ---- phase-2 topic projections (fp8 out) ----
    gemm_lds<false, unsigned char, 0, false><<<dim3(4, 16), 256, 0, stream>>>(
        xt2, B_t2, bias_t2, kv2, NT, 512, nullptr, nullptr, 0);

    // ---- messages into doc (td:16/dst, wd:16/dst, both fp8) ----
    msg_k<16, 16><<<dim3(ND), 256, 0, stream>>>(
        qd, 256,
        kv2, 512, 0, 256, src_td,
        w8, 1024, 512, 768, src_wd,
        rel_pri, 2, 3, tdoc, ND);

    // ---- doc update: mix -> LN ----
    gemm_w<false, float, 1, false, true><<<dim3(2, 79), 512, 0, stream>>>(
        tdoc, Wa1t, ba + 256, out_doc, ND, 256, feat_doc, skip, 1);
    ln_k<false><<<dim3(5000), 256, 0, stream>>>(out_doc, ln_g + 256, ln_b + 256, ND, nullptr);
}

// Round 14
// 254.737 us; speedup vs baseline: 1.0337x; 1.0337x over previous
//
#include <hip/hip_runtime.h>
#include <hip/hip_bf16.h>
#include <hip/hip_fp8.h>

typedef __attribute__((ext_vector_type(8))) short bf16x8;
typedef __attribute__((ext_vector_type(4))) float f32x4;
typedef __attribute__((ext_vector_type(2))) float f32x2;

constexpr int NT = 2000, NW = 50000, ND = 20000;
constexpr float INV_SQRT_DK = 0.17677669529663687f;  // 1/sqrt(32)

__device__ inline float bfu(unsigned short u) {
    return __uint_as_float(((unsigned int)u) << 16);
}
__device__ inline float blo(unsigned int u) { return __uint_as_float(u << 16); }
__device__ inline float bhi(unsigned int u) { return __uint_as_float(u & 0xffff0000u); }
__device__ inline short f2bf(float x) {
    __hip_bfloat16 h = __float2bfloat16(x);
    short s; __builtin_memcpy(&s, &h, 2); return s;
}

// ---- fp8 e4m3 (OCP) helpers: HW cvt with SW fallback ----
__device__ inline void dec4(unsigned int w, float* o) {
#if __has_builtin(__builtin_amdgcn_cvt_pk_f32_fp8)
    f32x2 a = __builtin_amdgcn_cvt_pk_f32_fp8(w, false);
    f32x2 b = __builtin_amdgcn_cvt_pk_f32_fp8(w, true);
    o[0] = a[0]; o[1] = a[1]; o[2] = b[0]; o[3] = b[1];
#else
    __hip_fp8_e4m3 t0, t1, t2, t3;
    t0.__x = (__hip_fp8_storage_t)(w & 0xff);
    t1.__x = (__hip_fp8_storage_t)((w >> 8) & 0xff);
    t2.__x = (__hip_fp8_storage_t)((w >> 16) & 0xff);
    t3.__x = (__hip_fp8_storage_t)((w >> 24) & 0xff);
    o[0] = (float)t0; o[1] = (float)t1; o[2] = (float)t2; o[3] = (float)t3;
#endif
}
__device__ inline unsigned char f2fp8(float v) {
#if __has_builtin(__builtin_amdgcn_cvt_pk_fp8_f32)
    return (unsigned char)(__builtin_amdgcn_cvt_pk_fp8_f32(v, v, 0u, false) & 0xff);
#else
    __hip_fp8_e4m3 h(v); return (unsigned char)h.__x;
#endif
}

// scalar stores (r9 epilogue)
__device__ inline void cstore(float* p, float v) { *p = v; }
__device__ inline void cstore(short* p, float v) { *p = f2bf(v); }
__device__ inline void cstore(unsigned char* p, float v) { *p = f2fp8(v); }

// packed 4-consecutive-column stores (swapped-operand epilogue)
__device__ inline void cstore4(float* p, float4 v) {
    *reinterpret_cast<float4*>(p) = v;
}
__device__ inline void cstore4(short* p, float4 v) {
    short4 s; s.x = f2bf(v.x); s.y = f2bf(v.y); s.z = f2bf(v.z); s.w = f2bf(v.w);
    *reinterpret_cast<short4*>(p) = s;
}
__device__ inline void cstore4(unsigned char* p, float4 v) {
#if __has_builtin(__builtin_amdgcn_cvt_pk_fp8_f32)
    unsigned int w = __builtin_amdgcn_cvt_pk_fp8_f32(v.x, v.y, 0u, false);
    w = __builtin_amdgcn_cvt_pk_fp8_f32(v.z, v.w, w, true);
    *reinterpret_cast<unsigned int*>(p) = w;
#else
    p[0] = f2fp8(v.x); p[1] = f2fp8(v.y); p[2] = f2fp8(v.z); p[3] = f2fp8(v.w);
#endif
}

__device__ inline void gload16(const short* g, short* l) {
    __builtin_amdgcn_global_load_lds(
        (const __attribute__((address_space(1))) void*)g,
        (__attribute__((address_space(3))) void*)l, 16, 0, 0);
}

// 32-element fp8 dot against fp32 q in registers
__device__ inline float dot32f8(const unsigned char* __restrict__ kp, const float* __restrict__ qh) {
    const uint4 u = *reinterpret_cast<const uint4*>(kp);
    const uint4 v = *reinterpret_cast<const uint4*>(kp + 16);
    const unsigned int ws[8] = {u.x, u.y, u.z, u.w, v.x, v.y, v.z, v.w};
    float d = 0.f;
    #pragma unroll
    for (int c = 0; c < 8; ++c) {
        float f[4];
        dec4(ws[c], f);
        d += qh[c * 4 + 0] * f[0] + qh[c * 4 + 1] * f[1]
           + qh[c * 4 + 2] * f[2] + qh[c * 4 + 3] * f[3];
    }
    return d;
}

// =====================================================================
// fold: per-relation head transforms folded into projection weights,
// written TRANSPOSED bf16 ([n][k]) into the packed B matrices.
// =====================================================================
__global__ __launch_bounds__(256) void fold_kernel(
    const float* __restrict__ Wk, const float* __restrict__ bk,
    const float* __restrict__ Wv, const float* __restrict__ bv,
    const float* __restrict__ rel_att, const float* __restrict__ rel_msg,
    short* __restrict__ B_t1, short* __restrict__ B_w, short* __restrict__ B_t2,
    float* __restrict__ bias_t1, float* __restrict__ bias_w, float* __restrict__ bias_t2)
{
    const int f = blockIdx.x >> 3, chunk = blockIdx.x & 7;
    const int rel = f >> 1, isV = f & 1;
    const int ntype = (rel == 1 || rel == 3) ? 1 : 0;
    const float* Wsrc = (isV ? Wv : Wk) + ntype * 65536;
    const float* bsrc = (isV ? bv : bk) + ntype * 256;
    const float* A    = (isV ? rel_msg : rel_att) + rel * 8192;  // [8][32][32]
    short* wdst; float* bdst;
    switch (f) {
        case 0: wdst = B_t1 + 65536;     bdst = bias_t1 + 256; break;  // K tt
        case 1: wdst = B_t1 + 2 * 65536; bdst = bias_t1 + 512; break;  // V tt
        case 2: wdst = B_w;              bdst = bias_w;        break;  // K wt
        case 3: wdst = B_w + 65536;      bdst = bias_w + 256;  break;  // V wt
        case 4: wdst = B_t2;             bdst = bias_t2;       break;  // K td
        case 5: wdst = B_t2 + 65536;     bdst = bias_t2 + 256; break;  // V td
        case 6: wdst = B_w + 2 * 65536;  bdst = bias_w + 512;  break;  // K wd
        default: wdst = B_w + 3 * 65536; bdst = bias_w + 768;  break;  // V wd
    }
    __shared__ float Wsh[32][256];
    const int tid = threadIdx.x;
    for (int i = 0; i < 32; ++i)
        Wsh[i][tid] = Wsrc[(chunk * 32 + i) * 256 + tid];
    __syncthreads();
    const int h = tid >> 5, o = tid & 31;
    float a[32];
    #pragma unroll
    for (int d = 0; d < 32; ++d) a[d] = A[h * 1024 + d * 32 + o];
    short tmp[32];
    #pragma unroll
    for (int r = 0; r < 32; ++r) {
        float s = 0.f;
        #pragma unroll
        for (int d = 0; d < 32; ++d) s = fmaf(Wsh[r][(h << 5) + d], a[d], s);
        tmp[r] = f2bf(s);
    }
    short* wp = wdst + tid * 256 + chunk * 32;
    #pragma unroll
    for (int r8 = 0; r8 < 4; ++r8) {
        bf16x8 v;
        #pragma unroll
        for (int t = 0; t < 8; ++t) v[t] = tmp[r8 * 8 + t];
        *reinterpret_cast<bf16x8*>(wp + r8 * 8) = v;
    }
    if (chunk == 0) {
        float s = 0.f;
        #pragma unroll
        for (int d = 0; d < 32; ++d) s = fmaf(bsrc[(h << 5) + d], a[d], s);
        bdst[tid] = s;
    }
}

struct TransP { const float* s[6]; short* d[6]; };
__global__ __launch_bounds__(256) void wtrans6(TransP p) {
    const int m = blockIdx.y, n = blockIdx.x, k = threadIdx.x;
    p.d[m][n * 256 + k] = f2bf(p.s[m][k * 256 + n]);
}

__global__ void copy_bias(const float* __restrict__ s, float* __restrict__ d) {
    d[threadIdx.x] = s[threadIdx.x];
}

// =====================================================================
// Packed epilogue (swapped-operand MFMA: thread owns 4 consecutive cols)
// =====================================================================
template <typename OutT, int EPI, int NI>
__device__ inline void epilogue(
    f32x4 (&acc)[NI][4], const float* __restrict__ bias, OutT* __restrict__ C,
    int M, int ldc, const float* __restrict__ extra,
    const float* __restrict__ skipv, int skipIdx,
    int row0, int col0, int wm, int wn, int r, int kb)
{
    float alpha = 0.f;
    if (EPI == 1) alpha = 1.f / (1.f + __expf(-skipv[skipIdx]));
    float4 b4[4];
    #pragma unroll
    for (int j = 0; j < 4; ++j)
        b4[j] = *reinterpret_cast<const float4*>(&bias[col0 + wn * 64 + j * 16 + kb * 4]);
    #pragma unroll
    for (int i = 0; i < NI; ++i) {
        const int rrow = row0 + wm * 64 + i * 16 + r;
        if (rrow >= M) continue;
        #pragma unroll
        for (int j = 0; j < 4; ++j) {
            const int cb = col0 + wn * 64 + j * 16 + kb * 4;
            float4 v;
            v.x = acc[i][j][0] + b4[j].x;
            v.y = acc[i][j][1] + b4[j].y;
            v.z = acc[i][j][2] + b4[j].z;
            v.w = acc[i][j][3] + b4[j].w;
            if (EPI == 1) {
                const float4 e = *reinterpret_cast<const float4*>(&extra[rrow * 256 + cb]);
                v.x = alpha * v.x + (1.f - alpha) * e.x;
                v.y = alpha * v.y + (1.f - alpha) * e.y;
                v.z = alpha * v.z + (1.f - alpha) * e.z;
                v.w = alpha * v.w + (1.f - alpha) * e.w;
            }
            if (EPI == 2) {
                const float4 e = *reinterpret_cast<const float4*>(&extra[rrow * 256 + cb]);
                v.x = tanhf(v.x + e.x);
                v.y = tanhf(v.y + e.y);
                v.z = tanhf(v.z + e.z);
                v.w = tanhf(v.w + e.w);
            }
            cstore4(C + rrow * ldc + cb, v);
        }
    }
}

// =====================================================================
// LDS-staged MFMA GEMM, 256 threads, 128x128 tile, BK=64, single-buffered,
// conflict-free XOR swizzle. Swapped MFMA + packed epilogue.
// =====================================================================
template <bool XF32, typename OutT, int EPI, bool SWZ>
__global__ __launch_bounds__(256) void gemm_lds(
    const void* __restrict__ Xv, const short* __restrict__ Wt,
    const float* __restrict__ bias, OutT* __restrict__ C,
    int M, int ldc, const float* __restrict__ extra,
    const float* __restrict__ skipv, int skipIdx)
{
    __shared__ short As[128 * 64];
    __shared__ short Bs[128 * 64];
    int bxi = blockIdx.x, byi = blockIdx.y;
    if constexpr (SWZ) {
        const int h = bxi + (int)gridDim.x * byi;
        const int i = h >> 3;
        byi = (h & 7) + 8 * (i >> 3);
        bxi = i & 7;
        if (byi * 128 >= M) return;
    }
    const int tid = threadIdx.x;
    const int wave = tid >> 6, lane = tid & 63;
    const int wm = wave >> 1, wn = wave & 1;
    const int r = lane & 15, kb = lane >> 4;
    const int col0 = bxi * 128;
    const int row0 = byi * 128;

    const int l8 = lane >> 3;
    const int c8 = lane & 7;
    const int swz8 = c8 ^ l8;
    f32x4 acc[4][4] = {};

    for (int k0 = 0; k0 < 256; k0 += 64) {
        if (k0) __syncthreads();
        if constexpr (XF32) {
            #pragma unroll
            for (int q = 0; q < 4; ++q) {
                const int rl = wave * 32 + q * 8 + l8;
                const int grow = min(row0 + rl, M - 1);
                const float* xp = (const float*)Xv + grow * 256 + k0 + c8 * 8;
                const float4 x0 = *reinterpret_cast<const float4*>(xp);
                const float4 x1 = *reinterpret_cast<const float4*>(xp + 4);
                bf16x8 v;
                v[0] = f2bf(x0.x); v[1] = f2bf(x0.y); v[2] = f2bf(x0.z); v[3] = f2bf(x0.w);
                v[4] = f2bf(x1.x); v[5] = f2bf(x1.y); v[6] = f2bf(x1.z); v[7] = f2bf(x1.w);
                *reinterpret_cast<bf16x8*>(As + rl * 64 + swz8 * 8) = v;
            }
        } else {
            #pragma unroll
            for (int q = 0; q < 4; ++q) {
                const int rl = wave * 32 + q * 8 + l8;
                const int grow = min(row0 + rl, M - 1);
                gload16((const short*)Xv + grow * 256 + k0 + swz8 * 8,
                        As + (wave * 32 + q * 8) * 64);
            }
        }
        #pragma unroll
        for (int q = 0; q < 4; ++q) {
            const int cl = wave * 32 + q * 8 + l8;
            gload16(Wt + (col0 + cl) * 256 + k0 + swz8 * 8,
                    Bs + (wave * 32 + q * 8) * 64);
        }
        __syncthreads();
        #pragma unroll
        for (int s = 0; s < 2; ++s) {
            const int csw = ((kb + 4 * s) ^ (r & 7)) * 8;
            bf16x8 af[4], bw[4];
            #pragma unroll
            for (int i = 0; i < 4; ++i) {
                af[i] = *reinterpret_cast<const bf16x8*>(As + (wm * 64 + i * 16 + r) * 64 + csw);
                bw[i] = *reinterpret_cast<const bf16x8*>(Bs + (wn * 64 + i * 16 + r) * 64 + csw);
            }
            #pragma unroll
            for (int i = 0; i < 4; ++i)
                #pragma unroll
                for (int j = 0; j < 4; ++j)
                    acc[i][j] = __builtin_amdgcn_mfma_f32_16x16x32_bf16(bw[j], af[i], acc[i][j], 0, 0, 0);
        }
    }
    epilogue<OutT, EPI, 4>(acc, bias, C, M, ldc, extra, skipv, skipIdx,
                           row0, col0, wm, wn, r, kb);
}

// =====================================================================
// Dual-output phase-1 topic projection: A=feat_topic (fp32), B=B_t1
// (768 cols packed: 0-255 -> q_t bf16 ldc=256, 256-767 -> kv1 fp8 ldc=512).
// =====================================================================
__global__ __launch_bounds__(256) void gemm_qkv(
    const float* __restrict__ X, const short* __restrict__ Wt,
    const float* __restrict__ bias, short* __restrict__ Qo,
    unsigned char* __restrict__ KVo, int M)
{
    __shared__ short As[128 * 64];
    __shared__ short Bs[128 * 64];
    const int bxi = blockIdx.x, byi = blockIdx.y;
    const int tid = threadIdx.x;
    const int wave = tid >> 6, lane = tid & 63;
    const int wm = wave >> 1, wn = wave & 1;
    const int r = lane & 15, kb = lane >> 4;
    const int col0 = bxi * 128;
    const int row0 = byi * 128;

    const int l8 = lane >> 3;
    const int c8 = lane & 7;
    const int swz8 = c8 ^ l8;
    f32x4 acc[4][4] = {};

    for (int k0 = 0; k0 < 256; k0 += 64) {
        if (k0) __syncthreads();
        #pragma unroll
        for (int q = 0; q < 4; ++q) {
            const int rl = wave * 32 + q * 8 + l8;
            const int grow = min(row0 + rl, M - 1);
            const float* xp = X + grow * 256 + k0 + c8 * 8;
            const float4 x0 = *reinterpret_cast<const float4*>(xp);
            const float4 x1 = *reinterpret_cast<const float4*>(xp + 4);
            bf16x8 v;
            v[0] = f2bf(x0.x); v[1] = f2bf(x0.y); v[2] = f2bf(x0.z); v[3] = f2bf(x0.w);
            v[4] = f2bf(x1.x); v[5] = f2bf(x1.y); v[6] = f2bf(x1.z); v[7] = f2bf(x1.w);
            *reinterpret_cast<bf16x8*>(As + rl * 64 + swz8 * 8) = v;
        }
        #pragma unroll
        for (int q = 0; q < 4; ++q) {
            const int cl = wave * 32 + q * 8 + l8;
            gload16(Wt + (col0 + cl) * 256 + k0 + swz8 * 8,
                    Bs + (wave * 32 + q * 8) * 64);
        }
        __syncthreads();
        #pragma unroll
        for (int s = 0; s < 2; ++s) {
            const int csw = ((kb + 4 * s) ^ (r & 7)) * 8;
            bf16x8 af[4], bw[4];
            #pragma unroll
            for (int i = 0; i < 4; ++i) {
                af[i] = *reinterpret_cast<const bf16x8*>(As + (wm * 64 + i * 16 + r) * 64 + csw);
                bw[i] = *reinterpret_cast<const bf16x8*>(Bs + (wn * 64 + i * 16 + r) * 64 + csw);
            }
            #pragma unroll
            for (int i = 0; i < 4; ++i)
                #pragma unroll
                for (int j = 0; j < 4; ++j)
                    acc[i][j] = __builtin_amdgcn_mfma_f32_16x16x32_bf16(bw[j], af[i], acc[i][j], 0, 0, 0);
        }
    }

    float4 b4[4];
    #pragma unroll
    for (int j = 0; j < 4; ++j)
        b4[j] = *reinterpret_cast<const float4*>(&bias[col0 + wn * 64 + j * 16 + kb * 4]);
    #pragma unroll
    for (int i = 0; i < 4; ++i) {
        const int rrow = row0 + wm * 64 + i * 16 + r;
        if (rrow >= M) continue;
        #pragma unroll
        for (int j = 0; j < 4; ++j) {
            const int cb = col0 + wn * 64 + j * 16 + kb * 4;
            float4 v;
            v.x = acc[i][j][0] + b4[j].x;
            v.y = acc[i][j][1] + b4[j].y;
            v.z = acc[i][j][2] + b4[j].z;
            v.w = acc[i][j][3] + b4[j].w;
            if (bxi < 2) cstore4(Qo + rrow * 256 + cb, v);
            else         cstore4(KVo + rrow * 512 + (cb - 256), v);
        }
    }
}

// =====================================================================
// Big-tile GEMM: 512 threads (8 waves 4x2), 256x128 tile, BK=64,
// single-buffered, same swizzle. SWAP selects packed epilogue (true)
// or r9-exact unswapped path (false; proven for word GEMM).
// =====================================================================
template <bool XF32, typename OutT, int EPI, bool SWZ, bool SWAP>
__global__ __launch_bounds__(512) void gemm_w(
    const void* __restrict__ Xv, const short* __restrict__ Wt,
    const float* __restrict__ bias, OutT* __restrict__ C,
    int M, int ldc, const float* __restrict__ extra,
    const float* __restrict__ skipv, int skipIdx)
{
    __shared__ short As[256 * 64];   // 32 KB
    __shared__ short Bs[128 * 64];   // 16 KB
    int bxi = blockIdx.x, byi = blockIdx.y;
    if constexpr (SWZ) {
        const int h = bxi + (int)gridDim.x * byi;
        const int i = h >> 3;
        byi = (h & 7) + 8 * (i >> 3);
        bxi = i & 7;
        if (byi * 256 >= M) return;
    }
    const int tid = threadIdx.x;
    const int wave = tid >> 6, lane = tid & 63;
    const int wm = wave >> 1, wn = wave & 1;      // 4x2 wave grid
    const int r = lane & 15, kb = lane >> 4;
    const int col0 = bxi * 128;
    const int row0 = byi * 256;

    const int l8 = lane >> 3;
    const int c8 = lane & 7;
    const int swz8 = c8 ^ l8;
    f32x4 acc[4][4] = {};

    for (int k0 = 0; k0 < 256; k0 += 64) {
        if (k0) __syncthreads();
        if constexpr (XF32) {
            #pragma unroll
            for (int q = 0; q < 4; ++q) {
                const int rl = wave * 32 + q * 8 + l8;
                const int grow = min(row0 + rl, M - 1);
                const float* xp = (const float*)Xv + grow * 256 + k0 + c8 * 8;
                const float4 x0 = *reinterpret_cast<const float4*>(xp);
                const float4 x1 = *reinterpret_cast<const float4*>(xp + 4);
                bf16x8 v;
                v[0] = f2bf(x0.x); v[1] = f2bf(x0.y); v[2] = f2bf(x0.z); v[3] = f2bf(x0.w);
                v[4] = f2bf(x1.x); v[5] = f2bf(x1.y); v[6] = f2bf(x1.z); v[7] = f2bf(x1.w);
                *reinterpret_cast<bf16x8*>(As + rl * 64 + swz8 * 8) = v;
            }
        } else {
            #pragma unroll
            for (int q = 0; q < 4; ++q) {
                const int rl = wave * 32 + q * 8 + l8;
                const int grow = min(row0 + rl, M - 1);
                gload16((const short*)Xv + grow * 256 + k0 + swz8 * 8,
                        As + (wave * 32 + q * 8) * 64);
            }
        }
        #pragma unroll
        for (int q = 0; q < 2; ++q) {
            const int cl = wave * 16 + q * 8 + l8;
            gload16(Wt + (col0 + cl) * 256 + k0 + swz8 * 8,
                    Bs + (wave * 16 + q * 8) * 64);
        }
        __syncthreads();
        #pragma unroll
        for (int s = 0; s < 2; ++s) {
            const int csw = ((kb + 4 * s) ^ (r & 7)) * 8;
            bf16x8 af[4], bw[4];
            #pragma unroll
            for (int i = 0; i < 4; ++i) {
                af[i] = *reinterpret_cast<const bf16x8*>(As + (wm * 64 + i * 16 + r) * 64 + csw);
                bw[i] = *reinterpret_cast<const bf16x8*>(Bs + (wn * 64 + i * 16 + r) * 64 + csw);
            }
            #pragma unroll
            for (int i = 0; i < 4; ++i)
                #pragma unroll
                for (int j = 0; j < 4; ++j) {
                    if constexpr (SWAP)
                        acc[i][j] = __builtin_amdgcn_mfma_f32_16x16x32_bf16(bw[j], af[i], acc[i][j], 0, 0, 0);
                    else
                        acc[i][j] = __builtin_amdgcn_mfma_f32_16x16x32_bf16(af[i], bw[j], acc[i][j], 0, 0, 0);
                }
        }
    }

    if constexpr (SWAP) {
        epilogue<OutT, EPI, 4>(acc, bias, C, M, ldc, extra, skipv, skipIdx,
                               row0, col0, wm, wn, r, kb);
    } else {
        // r9-exact scalar epilogue
        float alpha = 0.f;
        if (EPI == 1) alpha = 1.f / (1.f + __expf(-skipv[skipIdx]));
        #pragma unroll
        for (int i = 0; i < 4; ++i) {
            #pragma unroll
            for (int j = 0; j < 4; ++j) {
                const int col = col0 + wn * 64 + j * 16 + r;
                const float bc = bias[col];
                #pragma unroll
                for (int t = 0; t < 4; ++t) {
                    const int rrow = row0 + wm * 64 + i * 16 + kb * 4 + t;
                    if (rrow < M) {
                        float v = acc[i][j][t] + bc;
                        if (EPI == 1) v = alpha * v + (1.f - alpha) * extra[rrow * 256 + col];
                        if (EPI == 2) v = tanhf(v + extra[rrow * 256 + col]);
                        cstore(C + rrow * ldc + col, v);
                    }
                }
            }
        }
    }
}

// =====================================================================
// msg_k r14: score phase as before (per-head 32-lane groups, q in regs,
// register softmax pre-divided). Accumulate phase RELATION-SPLIT with
// 16B uint4 loads: rel=(tid>>4)&1, 16 col-threads x 16 fp8 per edge row.
// Partial sums in stride-17 padded LDS (conflict-free). Packed output.
// =====================================================================
template <int NE>
__device__ inline void rel_scores_f8(const unsigned char* __restrict__ kv, int ld, int koff,
                                     const int* __restrict__ sidx, int off, float scale,
                                     const float* __restrict__ qh, float* __restrict__ sc,
                                     int g, int l)
{
    constexpr int NL = NE / 32;
    float att[NL];
    #pragma unroll
    for (int t = 0; t < NL; ++t)
        att[t] = dot32f8(kv + (size_t)sidx[off + l + 32 * t] * ld + koff + g * 32, qh) * scale;
    float m = att[0];
    #pragma unroll
    for (int t = 1; t < NL; ++t) m = fmaxf(m, att[t]);
    #pragma unroll
    for (int o = 16; o > 0; o >>= 1) m = fmaxf(m, __shfl_xor(m, o));
    float ex[NL], s = 0.f;
    #pragma unroll
    for (int t = 0; t < NL; ++t) { ex[t] = __expf(att[t] - m); s += ex[t]; }
    #pragma unroll
    for (int o = 16; o > 0; o >>= 1) s += __shfl_xor(s, o);
    const float inv = 1.f / s;
    #pragma unroll
    for (int t = 0; t < NL; ++t) sc[(off + l + 32 * t) * 9 + g] = ex[t] * inv;
}

template <int NEA, int NEB>
__global__ __launch_bounds__(256) void msg_k(
    const short* __restrict__ q, int ldq,
    const unsigned char* __restrict__ kvA, int ldA, int koffA, int voffA,
    const int* __restrict__ srcA,
    const unsigned char* __restrict__ kvB, int ldB, int koffB, int voffB,
    const int* __restrict__ srcB,
    const float* __restrict__ relPri, int relA, int relB,
    short* __restrict__ out, int n_dst)
{
    constexpr int NET = NEA + NEB;
    const int j = blockIdx.x, tid = threadIdx.x;
    __shared__ float qsh[256];
    __shared__ int sidx[NET];
    __shared__ float sc[NET * 9];
    __shared__ float ps[8][544];   // [slot][rel*272 + ct16*17 + k], stride-17 pad

    if (tid < 64) {  // vectorized q load: 64 x 8B
        const ushort4 u = *reinterpret_cast<const ushort4*>(
            (const unsigned short*)q + j * ldq + tid * 4);
        float4 f; f.x = bfu(u.x); f.y = bfu(u.y); f.z = bfu(u.z); f.w = bfu(u.w);
        *reinterpret_cast<float4*>(qsh + tid * 4) = f;
    }
    if (tid < NEA) sidx[tid] = srcA[j + tid * n_dst];
    else if (tid < NET) sidx[tid] = srcB[j + (tid - NEA) * n_dst];
    __syncthreads();

    const int g = tid >> 5, l = tid & 31;
    float qr[32];
    #pragma unroll
    for (int c = 0; c < 8; ++c) {
        const float4 v = *reinterpret_cast<const float4*>(qsh + g * 32 + c * 4);
        qr[c * 4] = v.x; qr[c * 4 + 1] = v.y; qr[c * 4 + 2] = v.z; qr[c * 4 + 3] = v.w;
    }

    if constexpr (NEA == 16 && NEB == 16) {
        const int isB = l >> 4;
        const unsigned char* base = isB ? kvB + koffB : kvA + koffA;
        const int ld = isB ? ldB : ldA;
        const float scale = relPri[(isB ? relB : relA) * 8 + g] * INV_SQRT_DK;
        const float att = dot32f8(base + (size_t)sidx[l] * ld + g * 32, qr) * scale;
        float m = att;
        #pragma unroll
        for (int o = 8; o > 0; o >>= 1) m = fmaxf(m, __shfl_xor(m, o));
        const float ex = __expf(att - m);
        float s = ex;
        #pragma unroll
        for (int o = 8; o > 0; o >>= 1) s += __shfl_xor(s, o);
        sc[l * 9 + g] = ex / s;
    } else {
        rel_scores_f8<NEA>(kvA, ldA, koffA, sidx, 0,
                           relPri[relA * 8 + g] * INV_SQRT_DK, qr, sc, g, l);
        rel_scores_f8<NEB>(kvB, ldB, koffB, sidx, NEA,
                           relPri[relB * 8 + g] * INV_SQRT_DK, qr, sc, g, l);
    }
    __syncthreads();

    // ---- relation-split 16B accumulate ----
    const int ct16 = tid & 15;            // col group: cols ct16*16 .. +16
    const int rel  = (tid >> 4) & 1;      // 0 = A, 1 = B
    const int es   = tid >> 5;            // 8 edge slots
    const int hh   = ct16 >> 1;           // head of this col group
    const unsigned char* kvR = rel ? kvB : kvA;
    const int ldR   = rel ? ldB : ldA;
    const int voffR = rel ? voffB : voffA;
    const int offR  = rel ? NEA : 0;
    const int neR   = rel ? NEB : NEA;
    float acc[16] = {};
    for (int e = es; e < neR; e += 8) {
        const float w = sc[(offR + e) * 9 + hh];
        const uint4 u = *reinterpret_cast<const uint4*>(
            kvR + (size_t)sidx[offR + e] * ldR + voffR + ct16 * 16);
        float f[16];
        dec4(u.x, f); dec4(u.y, f + 4); dec4(u.z, f + 8); dec4(u.w, f + 12);
        #pragma unroll
        for (int k = 0; k < 16; ++k) acc[k] = fmaf(w, f[k], acc[k]);
    }
    {
        float* pp = &ps[es][rel * 272 + ct16 * 17];
        #pragma unroll
        for (int k = 0; k < 16; ++k) pp[k] = acc[k];
    }
    __syncthreads();

    // reduce 8 slots; column c = tid lives at [es2][rel*272 + (c>>4)*17 + (c&15)]
    const int ra = (tid >> 4) * 17 + (tid & 15);
    float rA = 0.f, rB = 0.f;
    #pragma unroll
    for (int e2 = 0; e2 < 8; ++e2) { rA += ps[e2][ra]; rB += ps[e2][272 + ra]; }
    const float val = 0.5f * (fmaxf(rA, 0.f) + fmaxf(rB, 0.f));
    unsigned short* ob = (unsigned short*)qsh;   // qsh dead; reuse as staging
    ob[tid] = (unsigned short)f2bf(val);
    __syncthreads();
    if (tid < 32) {
        const uint4 u = *reinterpret_cast<const uint4*>(ob + tid * 8);
        *reinterpret_cast<uint4*>((unsigned short*)out + j * 256 + tid * 8) = u;
    }
}

// =====================================================================
template <bool WB>
__global__ __launch_bounds__(256) void ln_k(
    float* __restrict__ data, const float* __restrict__ g,
    const float* __restrict__ b, int nrows, short* __restrict__ bfout)
{
    const int wid = threadIdx.x >> 6, lane = threadIdx.x & 63;
    const int row = blockIdx.x * 4 + wid;
    if (row >= nrows) return;
    float4 x = *reinterpret_cast<float4*>(data + row * 256 + lane * 4);
    float s  = x.x + x.y + x.z + x.w;
    float q2 = x.x * x.x + x.y * x.y + x.z * x.z + x.w * x.w;
    #pragma unroll
    for (int o = 32; o > 0; o >>= 1) { s += __shfl_xor(s, o); q2 += __shfl_xor(q2, o); }
    const float mu  = s * (1.f / 256.f);
    const float var = q2 * (1.f / 256.f) - mu * mu;
    const float rr = rsqrtf(var + 1e-5f);
    const float4 gg = *reinterpret_cast<const float4*>(g + lane * 4);
    const float4 bb = *reinterpret_cast<const float4*>(b + lane * 4);
    x.x = (x.x - mu) * rr * gg.x + bb.x;
    x.y = (x.y - mu) * rr * gg.y + bb.y;
    x.z = (x.z - mu) * rr * gg.z + bb.z;
    x.w = (x.w - mu) * rr * gg.w + bb.w;
    *reinterpret_cast<float4*>(data + row * 256 + lane * 4) = x;
    if (WB) {
        ushort4 u;
        u.x = (unsigned short)f2bf(x.x); u.y = (unsigned short)f2bf(x.y);
        u.z = (unsigned short)f2bf(x.z); u.w = (unsigned short)f2bf(x.w);
        *reinterpret_cast<ushort4*>((unsigned short*)bfout + row * 256 + lane * 4) = u;
    }
}

// =====================================================================
extern "C" void kernel_launch(void* const* d_in, const int* in_sizes, int n_in,
                              void* d_out, int out_size, void* d_ws, size_t ws_size,
                              hipStream_t stream)
{
    const float* feat_topic = (const float*)d_in[0];
    const float* feat_word  = (const float*)d_in[1];
    const float* feat_doc   = (const float*)d_in[2];
    const float* ht_prev    = (const float*)d_in[3];
    const float* Wk  = (const float*)d_in[4];
    const float* bk  = (const float*)d_in[5];
    const float* Wq  = (const float*)d_in[6];
    const float* bq  = (const float*)d_in[7];
    const float* Wv  = (const float*)d_in[8];
    const float* bv  = (const float*)d_in[9];
    const float* Wa  = (const float*)d_in[10];
    const float* ba  = (const float*)d_in[11];
    const float* ln_g = (const float*)d_in[12];
    const float* ln_b = (const float*)d_in[13];
    const float* skip = (const float*)d_in[14];
    const float* Wih  = (const float*)d_in[15];
    const float* Whh  = (const float*)d_in[16];
    const float* bih  = (const float*)d_in[17];
    const float* bhh  = (const float*)d_in[18];
    const float* rel_pri = (const float*)d_in[19];
    const float* rel_att = (const float*)d_in[20];
    const float* rel_msg = (const float*)d_in[21];
    const int* src_tt = (const int*)d_in[22];
    const int* src_wt = (const int*)d_in[24];
    const int* src_td = (const int*)d_in[26];
    const int* src_wd = (const int*)d_in[28];

    // ---- workspace layout ----
    short* B_t1 = (short*)d_ws;                 // 768*256
    short* B_w  = B_t1 + 196608;                // 1024*256
    short* B_t2 = B_w + 262144;                 // 512*256
    short* Wq2t = B_t2 + 131072;                // 5 x 256*256
    short* Whht = Wq2t + 65536;
    short* Wa0t = Whht + 65536;
    short* Wiht = Wa0t + 65536;
    short* Wa1t = Wiht + 65536;
    short* q_t  = Wa1t + 65536;                 // bf16 [2000][256]
    unsigned char* kv1 = (unsigned char*)(q_t + 512000);  // fp8 [2000][512]  K_tt|V_tt
    unsigned char* w8  = kv1 + 1024000;                   // fp8 [50000][1024] Kwt|Vwt|Kwd|Vwd
    unsigned char* kv2 = w8 + 51200000;                   // fp8 [2000][512]  K_td|V_td
    short* qd   = (short*)(kv2 + 1024000);      // bf16 [20000][256]
    short* ttop = qd + 5120000;                 // bf16 [2000][256]
    short* mixb = ttop + 512000;                // bf16 [2000][256]
    short* tdoc = mixb + 512000;                // bf16 [20000][256]
    short* xt2  = tdoc + 5120000;               // bf16 [2000][256]
    float* bias_t1 = (float*)(xt2 + 512000);    // 768
    float* bias_w  = bias_t1 + 768;             // 1024
    float* bias_t2 = bias_w + 1024;             // 512
    float* r2      = bias_t2 + 512;             // fp32 [2000][256]

    float* out_topic = (float*)d_out;
    float* out_doc   = out_topic + NT * 256;

    // ---- weight prep ----
    fold_kernel<<<dim3(64), 256, 0, stream>>>(Wk, bk, Wv, bv, rel_att, rel_msg,
                                              B_t1, B_w, B_t2, bias_t1, bias_w, bias_t2);
    TransP tp;
    tp.s[0] = Wq;            tp.d[0] = B_t1;   // Wq[topic]
    tp.s[1] = Wq + 131072;   tp.d[1] = Wq2t;   // Wq[doc]
    tp.s[2] = Whh;           tp.d[2] = Whht;
    tp.s[3] = Wih;           tp.d[3] = Wiht;
    tp.s[4] = Wa;            tp.d[4] = Wa0t;
    tp.s[5] = Wa + 65536;    tp.d[5] = Wa1t;
    wtrans6<<<dim3(256, 6), 256, 0, stream>>>(tp);
    copy_bias<<<dim3(1), 256, 0, stream>>>(bq, bias_t1);

    // ---- word GEMM: r12-exact (fp32-A reg-staged, unswapped, XCD swizzle) ----
    gemm_w<true, unsigned char, 0, true, false><<<dim3(8, 200), 512, 0, stream>>>(
        feat_word, B_w, bias_w, w8, NW, 1024, nullptr, nullptr, 0);

    // ---- phase-1 topic projections fused (q_t + kv1) ----
    gemm_qkv<<<dim3(6, 16), 256, 0, stream>>>(
        feat_topic, B_t1, bias_t1, q_t, kv1, NT);
    gemm_w<true, short, 0, false, true><<<dim3(2, 79), 512, 0, stream>>>(
        feat_doc, Wq2t, bq + 512, qd, ND, 256, nullptr, nullptr, 0);
    gemm_lds<true, float, 0, false><<<dim3(2, 16), 256, 0, stream>>>(
        ht_prev, Whht, bhh, r2, NT, 256, nullptr, nullptr, 0);

    // ---- messages into topic (tt:64/dst, wt:128/dst, both fp8) ----
    msg_k<64, 128><<<dim3(NT), 256, 0, stream>>>(
        q_t, 256,
        kv1, 512, 0, 256, src_tt,
        w8, 1024, 0, 256, src_wt,
        rel_pri, 0, 1, ttop, NT);

    // ---- topic update: mix -> RNN tanh -> LN ----
    gemm_lds<false, short, 1, false><<<dim3(2, 16), 256, 0, stream>>>(
        ttop, Wa0t, ba, mixb, NT, 256, feat_topic, skip, 0);
    gemm_lds<false, float, 2, false><<<dim3(2, 16), 256, 0, stream>>>(
        mixb, Wiht, bih, out_topic, NT, 256, r2, nullptr, 0);
    ln_k<true><<<dim3(500), 256, 0, stream>>>(out_topic, ln_g, ln_b, NT, xt2);

    // ---- phase-2 topic projections (fp8 out) ----
    gemm_lds<false, unsigned char, 0, false><<<dim3(4, 16), 256, 0, stream>>>(
        xt2, B_t2, bias_t2, kv2, NT, 512, nullptr, nullptr, 0);

    // ---- messages into doc (td:16/dst, wd:16/dst, both fp8) ----
    msg_k<16, 16><<<dim3(ND), 256, 0, stream>>>(
        qd, 256,
        kv2, 512, 0, 256, src_td,
        w8, 1024, 512, 768, src_wd,
        rel_pri, 2, 3, tdoc, ND);

    // ---- doc update: mix -> LN ----
    gemm_w<false, float, 1, false, true><<<dim3(2, 79), 512, 0, stream>>>(
        tdoc, Wa1t, ba + 256, out_doc, ND, 256, feat_doc, skip, 1);
    ln_k<false><<<dim3(5000), 256, 0, stream>>>(out_doc, ln_g + 256, ln_b + 256, ND, nullptr);
}

// Round 15
// 252.011 us; speedup vs baseline: 1.0449x; 1.0108x over previous
//
#include <hip/hip_runtime.h>
#include <hip/hip_bf16.h>
#include <hip/hip_fp8.h>

typedef __attribute__((ext_vector_type(8))) short bf16x8;
typedef __attribute__((ext_vector_type(4))) float f32x4;
typedef __attribute__((ext_vector_type(2))) float f32x2;

constexpr int NT = 2000, NW = 50000, ND = 20000;
constexpr float INV_SQRT_DK = 0.17677669529663687f;  // 1/sqrt(32)

__device__ inline float bfu(unsigned short u) {
    return __uint_as_float(((unsigned int)u) << 16);
}
__device__ inline float blo(unsigned int u) { return __uint_as_float(u << 16); }
__device__ inline float bhi(unsigned int u) { return __uint_as_float(u & 0xffff0000u); }
__device__ inline short f2bf(float x) {
    __hip_bfloat16 h = __float2bfloat16(x);
    short s; __builtin_memcpy(&s, &h, 2); return s;
}

// ---- fp8 e4m3 (OCP) helpers: HW cvt with SW fallback ----
__device__ inline void dec4(unsigned int w, float* o) {
#if __has_builtin(__builtin_amdgcn_cvt_pk_f32_fp8)
    f32x2 a = __builtin_amdgcn_cvt_pk_f32_fp8(w, false);
    f32x2 b = __builtin_amdgcn_cvt_pk_f32_fp8(w, true);
    o[0] = a[0]; o[1] = a[1]; o[2] = b[0]; o[3] = b[1];
#else
    __hip_fp8_e4m3 t0, t1, t2, t3;
    t0.__x = (__hip_fp8_storage_t)(w & 0xff);
    t1.__x = (__hip_fp8_storage_t)((w >> 8) & 0xff);
    t2.__x = (__hip_fp8_storage_t)((w >> 16) & 0xff);
    t3.__x = (__hip_fp8_storage_t)((w >> 24) & 0xff);
    o[0] = (float)t0; o[1] = (float)t1; o[2] = (float)t2; o[3] = (float)t3;
#endif
}
__device__ inline unsigned char f2fp8(float v) {
#if __has_builtin(__builtin_amdgcn_cvt_pk_fp8_f32)
    return (unsigned char)(__builtin_amdgcn_cvt_pk_fp8_f32(v, v, 0u, false) & 0xff);
#else
    __hip_fp8_e4m3 h(v); return (unsigned char)h.__x;
#endif
}

// scalar stores (r9 epilogue)
__device__ inline void cstore(float* p, float v) { *p = v; }
__device__ inline void cstore(short* p, float v) { *p = f2bf(v); }
__device__ inline void cstore(unsigned char* p, float v) { *p = f2fp8(v); }

// packed 4-consecutive-column stores (swapped-operand epilogue)
__device__ inline void cstore4(float* p, float4 v) {
    *reinterpret_cast<float4*>(p) = v;
}
__device__ inline void cstore4(short* p, float4 v) {
    short4 s; s.x = f2bf(v.x); s.y = f2bf(v.y); s.z = f2bf(v.z); s.w = f2bf(v.w);
    *reinterpret_cast<short4*>(p) = s;
}
__device__ inline void cstore4(unsigned char* p, float4 v) {
#if __has_builtin(__builtin_amdgcn_cvt_pk_fp8_f32)
    unsigned int w = __builtin_amdgcn_cvt_pk_fp8_f32(v.x, v.y, 0u, false);
    w = __builtin_amdgcn_cvt_pk_fp8_f32(v.z, v.w, w, true);
    *reinterpret_cast<unsigned int*>(p) = w;
#else
    p[0] = f2fp8(v.x); p[1] = f2fp8(v.y); p[2] = f2fp8(v.z); p[3] = f2fp8(v.w);
#endif
}

__device__ inline void gload16(const short* g, short* l) {
    __builtin_amdgcn_global_load_lds(
        (const __attribute__((address_space(1))) void*)g,
        (__attribute__((address_space(3))) void*)l, 16, 0, 0);
}

// 32-element fp8 dot against fp32 q in registers
__device__ inline float dot32f8(const unsigned char* __restrict__ kp, const float* __restrict__ qh) {
    const uint4 u = *reinterpret_cast<const uint4*>(kp);
    const uint4 v = *reinterpret_cast<const uint4*>(kp + 16);
    const unsigned int ws[8] = {u.x, u.y, u.z, u.w, v.x, v.y, v.z, v.w};
    float d = 0.f;
    #pragma unroll
    for (int c = 0; c < 8; ++c) {
        float f[4];
        dec4(ws[c], f);
        d += qh[c * 4 + 0] * f[0] + qh[c * 4 + 1] * f[1]
           + qh[c * 4 + 2] * f[2] + qh[c * 4 + 3] * f[3];
    }
    return d;
}

// =====================================================================
// fp32 -> bf16 convert: one 8-elem item per thread (max parallelism,
// no loop-carried dependence). grid = ceil(n8 / 256).
// =====================================================================
__global__ __launch_bounds__(256) void cvt_bf16(
    const float* __restrict__ src, short* __restrict__ dst, int n8)
{
    const int i = blockIdx.x * 256 + threadIdx.x;
    if (i >= n8) return;
    const float* p = src + (long)i * 8;
    const float4 x0 = *reinterpret_cast<const float4*>(p);
    const float4 x1 = *reinterpret_cast<const float4*>(p + 4);
    bf16x8 v;
    v[0] = f2bf(x0.x); v[1] = f2bf(x0.y); v[2] = f2bf(x0.z); v[3] = f2bf(x0.w);
    v[4] = f2bf(x1.x); v[5] = f2bf(x1.y); v[6] = f2bf(x1.z); v[7] = f2bf(x1.w);
    *reinterpret_cast<bf16x8*>(dst + (long)i * 8) = v;
}

// =====================================================================
// fold: per-relation head transforms folded into projection weights,
// written TRANSPOSED bf16 ([n][k]) into the packed B matrices.
// =====================================================================
__global__ __launch_bounds__(256) void fold_kernel(
    const float* __restrict__ Wk, const float* __restrict__ bk,
    const float* __restrict__ Wv, const float* __restrict__ bv,
    const float* __restrict__ rel_att, const float* __restrict__ rel_msg,
    short* __restrict__ B_t1, short* __restrict__ B_w, short* __restrict__ B_t2,
    float* __restrict__ bias_t1, float* __restrict__ bias_w, float* __restrict__ bias_t2)
{
    const int f = blockIdx.x >> 3, chunk = blockIdx.x & 7;
    const int rel = f >> 1, isV = f & 1;
    const int ntype = (rel == 1 || rel == 3) ? 1 : 0;
    const float* Wsrc = (isV ? Wv : Wk) + ntype * 65536;
    const float* bsrc = (isV ? bv : bk) + ntype * 256;
    const float* A    = (isV ? rel_msg : rel_att) + rel * 8192;  // [8][32][32]
    short* wdst; float* bdst;
    switch (f) {
        case 0: wdst = B_t1 + 65536;     bdst = bias_t1 + 256; break;  // K tt
        case 1: wdst = B_t1 + 2 * 65536; bdst = bias_t1 + 512; break;  // V tt
        case 2: wdst = B_w;              bdst = bias_w;        break;  // K wt
        case 3: wdst = B_w + 65536;      bdst = bias_w + 256;  break;  // V wt
        case 4: wdst = B_t2;             bdst = bias_t2;       break;  // K td
        case 5: wdst = B_t2 + 65536;     bdst = bias_t2 + 256; break;  // V td
        case 6: wdst = B_w + 2 * 65536;  bdst = bias_w + 512;  break;  // K wd
        default: wdst = B_w + 3 * 65536; bdst = bias_w + 768;  break;  // V wd
    }
    __shared__ float Wsh[32][256];
    const int tid = threadIdx.x;
    for (int i = 0; i < 32; ++i)
        Wsh[i][tid] = Wsrc[(chunk * 32 + i) * 256 + tid];
    __syncthreads();
    const int h = tid >> 5, o = tid & 31;
    float a[32];
    #pragma unroll
    for (int d = 0; d < 32; ++d) a[d] = A[h * 1024 + d * 32 + o];
    short tmp[32];
    #pragma unroll
    for (int r = 0; r < 32; ++r) {
        float s = 0.f;
        #pragma unroll
        for (int d = 0; d < 32; ++d) s = fmaf(Wsh[r][(h << 5) + d], a[d], s);
        tmp[r] = f2bf(s);
    }
    short* wp = wdst + tid * 256 + chunk * 32;
    #pragma unroll
    for (int r8 = 0; r8 < 4; ++r8) {
        bf16x8 v;
        #pragma unroll
        for (int t = 0; t < 8; ++t) v[t] = tmp[r8 * 8 + t];
        *reinterpret_cast<bf16x8*>(wp + r8 * 8) = v;
    }
    if (chunk == 0) {
        float s = 0.f;
        #pragma unroll
        for (int d = 0; d < 32; ++d) s = fmaf(bsrc[(h << 5) + d], a[d], s);
        bdst[tid] = s;
    }
}

struct TransP { const float* s[6]; short* d[6]; };
__global__ __launch_bounds__(256) void wtrans6(TransP p) {
    const int m = blockIdx.y, n = blockIdx.x, k = threadIdx.x;
    p.d[m][n * 256 + k] = f2bf(p.s[m][k * 256 + n]);
}

__global__ void copy_bias(const float* __restrict__ s, float* __restrict__ d) {
    d[threadIdx.x] = s[threadIdx.x];
}

// =====================================================================
// Packed epilogue (swapped-operand MFMA: thread owns 4 consecutive cols)
// =====================================================================
template <typename OutT, int EPI, int NI>
__device__ inline void epilogue(
    f32x4 (&acc)[NI][4], const float* __restrict__ bias, OutT* __restrict__ C,
    int M, int ldc, const float* __restrict__ extra,
    const float* __restrict__ skipv, int skipIdx,
    int row0, int col0, int wm, int wn, int r, int kb)
{
    float alpha = 0.f;
    if (EPI == 1) alpha = 1.f / (1.f + __expf(-skipv[skipIdx]));
    float4 b4[4];
    #pragma unroll
    for (int j = 0; j < 4; ++j)
        b4[j] = *reinterpret_cast<const float4*>(&bias[col0 + wn * 64 + j * 16 + kb * 4]);
    #pragma unroll
    for (int i = 0; i < NI; ++i) {
        const int rrow = row0 + wm * 64 + i * 16 + r;
        if (rrow >= M) continue;
        #pragma unroll
        for (int j = 0; j < 4; ++j) {
            const int cb = col0 + wn * 64 + j * 16 + kb * 4;
            float4 v;
            v.x = acc[i][j][0] + b4[j].x;
            v.y = acc[i][j][1] + b4[j].y;
            v.z = acc[i][j][2] + b4[j].z;
            v.w = acc[i][j][3] + b4[j].w;
            if (EPI == 1) {
                const float4 e = *reinterpret_cast<const float4*>(&extra[rrow * 256 + cb]);
                v.x = alpha * v.x + (1.f - alpha) * e.x;
                v.y = alpha * v.y + (1.f - alpha) * e.y;
                v.z = alpha * v.z + (1.f - alpha) * e.z;
                v.w = alpha * v.w + (1.f - alpha) * e.w;
            }
            if (EPI == 2) {
                const float4 e = *reinterpret_cast<const float4*>(&extra[rrow * 256 + cb]);
                v.x = tanhf(v.x + e.x);
                v.y = tanhf(v.y + e.y);
                v.z = tanhf(v.z + e.z);
                v.w = tanhf(v.w + e.w);
            }
            cstore4(C + rrow * ldc + cb, v);
        }
    }
}

// =====================================================================
// LDS-staged MFMA GEMM, 256 threads, 128x128 tile, BK=64, single-buffered,
// conflict-free XOR swizzle. Swapped MFMA + packed epilogue.
// =====================================================================
template <bool XF32, typename OutT, int EPI, bool SWZ>
__global__ __launch_bounds__(256) void gemm_lds(
    const void* __restrict__ Xv, const short* __restrict__ Wt,
    const float* __restrict__ bias, OutT* __restrict__ C,
    int M, int ldc, const float* __restrict__ extra,
    const float* __restrict__ skipv, int skipIdx)
{
    __shared__ short As[128 * 64];
    __shared__ short Bs[128 * 64];
    int bxi = blockIdx.x, byi = blockIdx.y;
    if constexpr (SWZ) {
        const int h = bxi + (int)gridDim.x * byi;
        const int i = h >> 3;
        byi = (h & 7) + 8 * (i >> 3);
        bxi = i & 7;
        if (byi * 128 >= M) return;
    }
    const int tid = threadIdx.x;
    const int wave = tid >> 6, lane = tid & 63;
    const int wm = wave >> 1, wn = wave & 1;
    const int r = lane & 15, kb = lane >> 4;
    const int col0 = bxi * 128;
    const int row0 = byi * 128;

    const int l8 = lane >> 3;
    const int c8 = lane & 7;
    const int swz8 = c8 ^ l8;
    f32x4 acc[4][4] = {};

    for (int k0 = 0; k0 < 256; k0 += 64) {
        if (k0) __syncthreads();
        if constexpr (XF32) {
            #pragma unroll
            for (int q = 0; q < 4; ++q) {
                const int rl = wave * 32 + q * 8 + l8;
                const int grow = min(row0 + rl, M - 1);
                const float* xp = (const float*)Xv + grow * 256 + k0 + c8 * 8;
                const float4 x0 = *reinterpret_cast<const float4*>(xp);
                const float4 x1 = *reinterpret_cast<const float4*>(xp + 4);
                bf16x8 v;
                v[0] = f2bf(x0.x); v[1] = f2bf(x0.y); v[2] = f2bf(x0.z); v[3] = f2bf(x0.w);
                v[4] = f2bf(x1.x); v[5] = f2bf(x1.y); v[6] = f2bf(x1.z); v[7] = f2bf(x1.w);
                *reinterpret_cast<bf16x8*>(As + rl * 64 + swz8 * 8) = v;
            }
        } else {
            #pragma unroll
            for (int q = 0; q < 4; ++q) {
                const int rl = wave * 32 + q * 8 + l8;
                const int grow = min(row0 + rl, M - 1);
                gload16((const short*)Xv + grow * 256 + k0 + swz8 * 8,
                        As + (wave * 32 + q * 8) * 64);
            }
        }
        #pragma unroll
        for (int q = 0; q < 4; ++q) {
            const int cl = wave * 32 + q * 8 + l8;
            gload16(Wt + (col0 + cl) * 256 + k0 + swz8 * 8,
                    Bs + (wave * 32 + q * 8) * 64);
        }
        __syncthreads();
        #pragma unroll
        for (int s = 0; s < 2; ++s) {
            const int csw = ((kb + 4 * s) ^ (r & 7)) * 8;
            bf16x8 af[4], bw[4];
            #pragma unroll
            for (int i = 0; i < 4; ++i) {
                af[i] = *reinterpret_cast<const bf16x8*>(As + (wm * 64 + i * 16 + r) * 64 + csw);
                bw[i] = *reinterpret_cast<const bf16x8*>(Bs + (wn * 64 + i * 16 + r) * 64 + csw);
            }
            #pragma unroll
            for (int i = 0; i < 4; ++i)
                #pragma unroll
                for (int j = 0; j < 4; ++j)
                    acc[i][j] = __builtin_amdgcn_mfma_f32_16x16x32_bf16(bw[j], af[i], acc[i][j], 0, 0, 0);
        }
    }
    epilogue<OutT, EPI, 4>(acc, bias, C, M, ldc, extra, skipv, skipIdx,
                           row0, col0, wm, wn, r, kb);
}

// =====================================================================
// Merged phase-1 small-GEMM kernel, grid (8,16):
//   bxi 0..5: A=feat_topic, B=B_t1 (768 cols) -> q_t (bf16) / kv1 (fp8)
//   bxi 6..7: A=ht_prev,   B=Whht (256 cols) -> r2 (fp32)
// Swapped MFMA + packed stores; block-uniform routing.
// =====================================================================
__global__ __launch_bounds__(256) void gemm_qkv(
    const float* __restrict__ X, const short* __restrict__ Wt,
    const float* __restrict__ bias, short* __restrict__ Qo,
    unsigned char* __restrict__ KVo, int M,
    const float* __restrict__ X2, const short* __restrict__ Wt2,
    const float* __restrict__ bias2, float* __restrict__ Ro)
{
    __shared__ short As[128 * 64];
    __shared__ short Bs[128 * 64];
    const int bxi = blockIdx.x, byi = blockIdx.y;
    const bool isR = bxi >= 6;
    const float* Xp = isR ? X2 : X;
    const short* Wp = isR ? Wt2 : Wt;
    const float* bp = isR ? bias2 : bias;
    const int colW = isR ? (bxi - 6) * 128 : bxi * 128;
    const int tid = threadIdx.x;
    const int wave = tid >> 6, lane = tid & 63;
    const int wm = wave >> 1, wn = wave & 1;
    const int r = lane & 15, kb = lane >> 4;
    const int row0 = byi * 128;

    const int l8 = lane >> 3;
    const int c8 = lane & 7;
    const int swz8 = c8 ^ l8;
    f32x4 acc[4][4] = {};

    for (int k0 = 0; k0 < 256; k0 += 64) {
        if (k0) __syncthreads();
        #pragma unroll
        for (int q = 0; q < 4; ++q) {
            const int rl = wave * 32 + q * 8 + l8;
            const int grow = min(row0 + rl, M - 1);
            const float* xp = Xp + grow * 256 + k0 + c8 * 8;
            const float4 x0 = *reinterpret_cast<const float4*>(xp);
            const float4 x1 = *reinterpret_cast<const float4*>(xp + 4);
            bf16x8 v;
            v[0] = f2bf(x0.x); v[1] = f2bf(x0.y); v[2] = f2bf(x0.z); v[3] = f2bf(x0.w);
            v[4] = f2bf(x1.x); v[5] = f2bf(x1.y); v[6] = f2bf(x1.z); v[7] = f2bf(x1.w);
            *reinterpret_cast<bf16x8*>(As + rl * 64 + swz8 * 8) = v;
        }
        #pragma unroll
        for (int q = 0; q < 4; ++q) {
            const int cl = wave * 32 + q * 8 + l8;
            gload16(Wp + (colW + cl) * 256 + k0 + swz8 * 8,
                    Bs + (wave * 32 + q * 8) * 64);
        }
        __syncthreads();
        #pragma unroll
        for (int s = 0; s < 2; ++s) {
            const int csw = ((kb + 4 * s) ^ (r & 7)) * 8;
            bf16x8 af[4], bw[4];
            #pragma unroll
            for (int i = 0; i < 4; ++i) {
                af[i] = *reinterpret_cast<const bf16x8*>(As + (wm * 64 + i * 16 + r) * 64 + csw);
                bw[i] = *reinterpret_cast<const bf16x8*>(Bs + (wn * 64 + i * 16 + r) * 64 + csw);
            }
            #pragma unroll
            for (int i = 0; i < 4; ++i)
                #pragma unroll
                for (int j = 0; j < 4; ++j)
                    acc[i][j] = __builtin_amdgcn_mfma_f32_16x16x32_bf16(bw[j], af[i], acc[i][j], 0, 0, 0);
        }
    }

    float4 b4[4];
    #pragma unroll
    for (int j = 0; j < 4; ++j)
        b4[j] = *reinterpret_cast<const float4*>(&bp[colW + wn * 64 + j * 16 + kb * 4]);
    #pragma unroll
    for (int i = 0; i < 4; ++i) {
        const int rrow = row0 + wm * 64 + i * 16 + r;
        if (rrow >= M) continue;
        #pragma unroll
        for (int j = 0; j < 4; ++j) {
            const int cb = colW + wn * 64 + j * 16 + kb * 4;
            float4 v;
            v.x = acc[i][j][0] + b4[j].x;
            v.y = acc[i][j][1] + b4[j].y;
            v.z = acc[i][j][2] + b4[j].z;
            v.w = acc[i][j][3] + b4[j].w;
            if (isR)          cstore4(Ro + rrow * 256 + cb, v);
            else if (bxi < 2) cstore4(Qo + rrow * 256 + cb, v);
            else              cstore4(KVo + rrow * 512 + (cb - 256), v);
        }
    }
}

// =====================================================================
// Big-tile GEMM: 512 threads (8 waves 4x2), 256x128 tile, BK=64,
// single-buffered, same swizzle. SWAP selects packed epilogue (true)
// or r9-exact unswapped path (false; proven for word GEMM).
// =====================================================================
template <bool XF32, typename OutT, int EPI, bool SWZ, bool SWAP>
__global__ __launch_bounds__(512) void gemm_w(
    const void* __restrict__ Xv, const short* __restrict__ Wt,
    const float* __restrict__ bias, OutT* __restrict__ C,
    int M, int ldc, const float* __restrict__ extra,
    const float* __restrict__ skipv, int skipIdx)
{
    __shared__ short As[256 * 64];   // 32 KB
    __shared__ short Bs[128 * 64];   // 16 KB
    int bxi = blockIdx.x, byi = blockIdx.y;
    if constexpr (SWZ) {
        const int h = bxi + (int)gridDim.x * byi;
        const int i = h >> 3;
        byi = (h & 7) + 8 * (i >> 3);
        bxi = i & 7;
        if (byi * 256 >= M) return;
    }
    const int tid = threadIdx.x;
    const int wave = tid >> 6, lane = tid & 63;
    const int wm = wave >> 1, wn = wave & 1;      // 4x2 wave grid
    const int r = lane & 15, kb = lane >> 4;
    const int col0 = bxi * 128;
    const int row0 = byi * 256;

    const int l8 = lane >> 3;
    const int c8 = lane & 7;
    const int swz8 = c8 ^ l8;
    f32x4 acc[4][4] = {};

    for (int k0 = 0; k0 < 256; k0 += 64) {
        if (k0) __syncthreads();
        if constexpr (XF32) {
            #pragma unroll
            for (int q = 0; q < 4; ++q) {
                const int rl = wave * 32 + q * 8 + l8;
                const int grow = min(row0 + rl, M - 1);
                const float* xp = (const float*)Xv + grow * 256 + k0 + c8 * 8;
                const float4 x0 = *reinterpret_cast<const float4*>(xp);
                const float4 x1 = *reinterpret_cast<const float4*>(xp + 4);
                bf16x8 v;
                v[0] = f2bf(x0.x); v[1] = f2bf(x0.y); v[2] = f2bf(x0.z); v[3] = f2bf(x0.w);
                v[4] = f2bf(x1.x); v[5] = f2bf(x1.y); v[6] = f2bf(x1.z); v[7] = f2bf(x1.w);
                *reinterpret_cast<bf16x8*>(As + rl * 64 + swz8 * 8) = v;
            }
        } else {
            #pragma unroll
            for (int q = 0; q < 4; ++q) {
                const int rl = wave * 32 + q * 8 + l8;
                const int grow = min(row0 + rl, M - 1);
                gload16((const short*)Xv + grow * 256 + k0 + swz8 * 8,
                        As + (wave * 32 + q * 8) * 64);
            }
        }
        #pragma unroll
        for (int q = 0; q < 2; ++q) {
            const int cl = wave * 16 + q * 8 + l8;
            gload16(Wt + (col0 + cl) * 256 + k0 + swz8 * 8,
                    Bs + (wave * 16 + q * 8) * 64);
        }
        __syncthreads();
        #pragma unroll
        for (int s = 0; s < 2; ++s) {
            const int csw = ((kb + 4 * s) ^ (r & 7)) * 8;
            bf16x8 af[4], bw[4];
            #pragma unroll
            for (int i = 0; i < 4; ++i) {
                af[i] = *reinterpret_cast<const bf16x8*>(As + (wm * 64 + i * 16 + r) * 64 + csw);
                bw[i] = *reinterpret_cast<const bf16x8*>(Bs + (wn * 64 + i * 16 + r) * 64 + csw);
            }
            #pragma unroll
            for (int i = 0; i < 4; ++i)
                #pragma unroll
                for (int j = 0; j < 4; ++j) {
                    if constexpr (SWAP)
                        acc[i][j] = __builtin_amdgcn_mfma_f32_16x16x32_bf16(bw[j], af[i], acc[i][j], 0, 0, 0);
                    else
                        acc[i][j] = __builtin_amdgcn_mfma_f32_16x16x32_bf16(af[i], bw[j], acc[i][j], 0, 0, 0);
                }
        }
    }

    if constexpr (SWAP) {
        epilogue<OutT, EPI, 4>(acc, bias, C, M, ldc, extra, skipv, skipIdx,
                               row0, col0, wm, wn, r, kb);
    } else {
        // r9-exact scalar epilogue
        float alpha = 0.f;
        if (EPI == 1) alpha = 1.f / (1.f + __expf(-skipv[skipIdx]));
        #pragma unroll
        for (int i = 0; i < 4; ++i) {
            #pragma unroll
            for (int j = 0; j < 4; ++j) {
                const int col = col0 + wn * 64 + j * 16 + r;
                const float bc = bias[col];
                #pragma unroll
                for (int t = 0; t < 4; ++t) {
                    const int rrow = row0 + wm * 64 + i * 16 + kb * 4 + t;
                    if (rrow < M) {
                        float v = acc[i][j][t] + bc;
                        if (EPI == 1) v = alpha * v + (1.f - alpha) * extra[rrow * 256 + col];
                        if (EPI == 2) v = tanhf(v + extra[rrow * 256 + col]);
                        cstore(C + rrow * ldc + col, v);
                    }
                }
            }
        }
    }
}

// =====================================================================
// msg_k (r14 structure): per-head 32-lane score groups, q in regs,
// register softmax pre-divided; relation-split 16B uint4 accumulate;
// stride-17 padded partial sums; packed bf16 output.
// =====================================================================
template <int NE>
__device__ inline void rel_scores_f8(const unsigned char* __restrict__ kv, int ld, int koff,
                                     const int* __restrict__ sidx, int off, float scale,
                                     const float* __restrict__ qh, float* __restrict__ sc,
                                     int g, int l)
{
    constexpr int NL = NE / 32;
    float att[NL];
    #pragma unroll
    for (int t = 0; t < NL; ++t)
        att[t] = dot32f8(kv + (size_t)sidx[off + l + 32 * t] * ld + koff + g * 32, qh) * scale;
    float m = att[0];
    #pragma unroll
    for (int t = 1; t < NL; ++t) m = fmaxf(m, att[t]);
    #pragma unroll
    for (int o = 16; o > 0; o >>= 1) m = fmaxf(m, __shfl_xor(m, o));
    float ex[NL], s = 0.f;
    #pragma unroll
    for (int t = 0; t < NL; ++t) { ex[t] = __expf(att[t] - m); s += ex[t]; }
    #pragma unroll
    for (int o = 16; o > 0; o >>= 1) s += __shfl_xor(s, o);
    const float inv = 1.f / s;
    #pragma unroll
    for (int t = 0; t < NL; ++t) sc[(off + l + 32 * t) * 9 + g] = ex[t] * inv;
}

template <int NEA, int NEB>
__global__ __launch_bounds__(256) void msg_k(
    const short* __restrict__ q, int ldq,
    const unsigned char* __restrict__ kvA, int ldA, int koffA, int voffA,
    const int* __restrict__ srcA,
    const unsigned char* __restrict__ kvB, int ldB, int koffB, int voffB,
    const int* __restrict__ srcB,
    const float* __restrict__ relPri, int relA, int relB,
    short* __restrict__ out, int n_dst)
{
    constexpr int NET = NEA + NEB;
    const int j = blockIdx.x, tid = threadIdx.x;
    __shared__ float qsh[256];
    __shared__ int sidx[NET];
    __shared__ float sc[NET * 9];
    __shared__ float ps[8][544];   // [slot][rel*272 + ct16*17 + k]

    if (tid < 64) {  // vectorized q load: 64 x 8B
        const ushort4 u = *reinterpret_cast<const ushort4*>(
            (const unsigned short*)q + j * ldq + tid * 4);
        float4 f; f.x = bfu(u.x); f.y = bfu(u.y); f.z = bfu(u.z); f.w = bfu(u.w);
        *reinterpret_cast<float4*>(qsh + tid * 4) = f;
    }
    if (tid < NEA) sidx[tid] = srcA[j + tid * n_dst];
    else if (tid < NET) sidx[tid] = srcB[j + (tid - NEA) * n_dst];
    __syncthreads();

    const int g = tid >> 5, l = tid & 31;
    float qr[32];
    #pragma unroll
    for (int c = 0; c < 8; ++c) {
        const float4 v = *reinterpret_cast<const float4*>(qsh + g * 32 + c * 4);
        qr[c * 4] = v.x; qr[c * 4 + 1] = v.y; qr[c * 4 + 2] = v.z; qr[c * 4 + 3] = v.w;
    }

    if constexpr (NEA == 16 && NEB == 16) {
        const int isB = l >> 4;
        const unsigned char* base = isB ? kvB + koffB : kvA + koffA;
        const int ld = isB ? ldB : ldA;
        const float scale = relPri[(isB ? relB : relA) * 8 + g] * INV_SQRT_DK;
        const float att = dot32f8(base + (size_t)sidx[l] * ld + g * 32, qr) * scale;
        float m = att;
        #pragma unroll
        for (int o = 8; o > 0; o >>= 1) m = fmaxf(m, __shfl_xor(m, o));
        const float ex = __expf(att - m);
        float s = ex;
        #pragma unroll
        for (int o = 8; o > 0; o >>= 1) s += __shfl_xor(s, o);
        sc[l * 9 + g] = ex / s;
    } else {
        rel_scores_f8<NEA>(kvA, ldA, koffA, sidx, 0,
                           relPri[relA * 8 + g] * INV_SQRT_DK, qr, sc, g, l);
        rel_scores_f8<NEB>(kvB, ldB, koffB, sidx, NEA,
                           relPri[relB * 8 + g] * INV_SQRT_DK, qr, sc, g, l);
    }
    __syncthreads();

    // ---- relation-split 16B accumulate ----
    const int ct16 = tid & 15;
    const int rel  = (tid >> 4) & 1;
    const int es   = tid >> 5;
    const int hh   = ct16 >> 1;
    const unsigned char* kvR = rel ? kvB : kvA;
    const int ldR   = rel ? ldB : ldA;
    const int voffR = rel ? voffB : voffA;
    const int offR  = rel ? NEA : 0;
    const int neR   = rel ? NEB : NEA;
    float acc[16] = {};
    for (int e = es; e < neR; e += 8) {
        const float w = sc[(offR + e) * 9 + hh];
        const uint4 u = *reinterpret_cast<const uint4*>(
            kvR + (size_t)sidx[offR + e] * ldR + voffR + ct16 * 16);
        float f[16];
        dec4(u.x, f); dec4(u.y, f + 4); dec4(u.z, f + 8); dec4(u.w, f + 12);
        #pragma unroll
        for (int k = 0; k < 16; ++k) acc[k] = fmaf(w, f[k], acc[k]);
    }
    {
        float* pp = &ps[es][rel * 272 + ct16 * 17];
        #pragma unroll
        for (int k = 0; k < 16; ++k) pp[k] = acc[k];
    }
    __syncthreads();

    const int ra = (tid >> 4) * 17 + (tid & 15);
    float rA = 0.f, rB = 0.f;
    #pragma unroll
    for (int e2 = 0; e2 < 8; ++e2) { rA += ps[e2][ra]; rB += ps[e2][272 + ra]; }
    const float val = 0.5f * (fmaxf(rA, 0.f) + fmaxf(rB, 0.f));
    unsigned short* ob = (unsigned short*)qsh;
    ob[tid] = (unsigned short)f2bf(val);
    __syncthreads();
    if (tid < 32) {
        const uint4 u = *reinterpret_cast<const uint4*>(ob + tid * 8);
        *reinterpret_cast<uint4*>((unsigned short*)out + j * 256 + tid * 8) = u;
    }
}

// =====================================================================
template <bool WB>
__global__ __launch_bounds__(256) void ln_k(
    float* __restrict__ data, const float* __restrict__ g,
    const float* __restrict__ b, int nrows, short* __restrict__ bfout)
{
    const int wid = threadIdx.x >> 6, lane = threadIdx.x & 63;
    const int row = blockIdx.x * 4 + wid;
    if (row >= nrows) return;
    float4 x = *reinterpret_cast<float4*>(data + row * 256 + lane * 4);
    float s  = x.x + x.y + x.z + x.w;
    float q2 = x.x * x.x + x.y * x.y + x.z * x.z + x.w * x.w;
    #pragma unroll
    for (int o = 32; o > 0; o >>= 1) { s += __shfl_xor(s, o); q2 += __shfl_xor(q2, o); }
    const float mu  = s * (1.f / 256.f);
    const float var = q2 * (1.f / 256.f) - mu * mu;
    const float rr = rsqrtf(var + 1e-5f);
    const float4 gg = *reinterpret_cast<const float4*>(g + lane * 4);
    const float4 bb = *reinterpret_cast<const float4*>(b + lane * 4);
    x.x = (x.x - mu) * rr * gg.x + bb.x;
    x.y = (x.y - mu) * rr * gg.y + bb.y;
    x.z = (x.z - mu) * rr * gg.z + bb.z;
    x.w = (x.w - mu) * rr * gg.w + bb.w;
    *reinterpret_cast<float4*>(data + row * 256 + lane * 4) = x;
    if (WB) {
        ushort4 u;
        u.x = (unsigned short)f2bf(x.x); u.y = (unsigned short)f2bf(x.y);
        u.z = (unsigned short)f2bf(x.z); u.w = (unsigned short)f2bf(x.w);
        *reinterpret_cast<ushort4*>((unsigned short*)bfout + row * 256 + lane * 4) = u;
    }
}

// =====================================================================
extern "C" void kernel_launch(void* const* d_in, const int* in_sizes, int n_in,
                              void* d_out, int out_size, void* d_ws, size_t ws_size,
                              hipStream_t stream)
{
    const float* feat_topic = (const float*)d_in[0];
    const float* feat_word  = (const float*)d_in[1];
    const float* feat_doc   = (const float*)d_in[2];
    const float* ht_prev    = (const float*)d_in[3];
    const float* Wk  = (const float*)d_in[4];
    const float* bk  = (const float*)d_in[5];
    const float* Wq  = (const float*)d_in[6];
    const float* bq  = (const float*)d_in[7];
    const float* Wv  = (const float*)d_in[8];
    const float* bv  = (const float*)d_in[9];
    const float* Wa  = (const float*)d_in[10];
    const float* ba  = (const float*)d_in[11];
    const float* ln_g = (const float*)d_in[12];
    const float* ln_b = (const float*)d_in[13];
    const float* skip = (const float*)d_in[14];
    const float* Wih  = (const float*)d_in[15];
    const float* Whh  = (const float*)d_in[16];
    const float* bih  = (const float*)d_in[17];
    const float* bhh  = (const float*)d_in[18];
    const float* rel_pri = (const float*)d_in[19];
    const float* rel_att = (const float*)d_in[20];
    const float* rel_msg = (const float*)d_in[21];
    const int* src_tt = (const int*)d_in[22];
    const int* src_wt = (const int*)d_in[24];
    const int* src_td = (const int*)d_in[26];
    const int* src_wd = (const int*)d_in[28];

    // ---- workspace layout ----
    short* B_t1 = (short*)d_ws;                 // 768*256
    short* B_w  = B_t1 + 196608;                // 1024*256
    short* B_t2 = B_w + 262144;                 // 512*256
    short* Wq2t = B_t2 + 131072;                // 5 x 256*256
    short* Whht = Wq2t + 65536;
    short* Wa0t = Whht + 65536;
    short* Wiht = Wa0t + 65536;
    short* Wa1t = Wiht + 65536;
    short* q_t  = Wa1t + 65536;                 // bf16 [2000][256]
    unsigned char* kv1 = (unsigned char*)(q_t + 512000);  // fp8 [2000][512]  K_tt|V_tt
    unsigned char* w8  = kv1 + 1024000;                   // fp8 [50000][1024] Kwt|Vwt|Kwd|Vwd
    unsigned char* kv2 = w8 + 51200000;                   // fp8 [2000][512]  K_td|V_td
    short* qd   = (short*)(kv2 + 1024000);      // bf16 [20000][256]
    short* ttop = qd + 5120000;                 // bf16 [2000][256]
    short* mixb = ttop + 512000;                // bf16 [2000][256]
    short* tdoc = mixb + 512000;                // bf16 [20000][256]
    short* xt2  = tdoc + 5120000;               // bf16 [2000][256]
    float* bias_t1 = (float*)(xt2 + 512000);    // 768
    float* bias_w  = bias_t1 + 768;             // 1024
    float* bias_t2 = bias_w + 1024;             // 512
    float* r2      = bias_t2 + 512;             // fp32 [2000][256]
    short* wfb     = (short*)(r2 + 512000);     // bf16 [50000][256] feat_word copy

    float* out_topic = (float*)d_out;
    float* out_doc   = out_topic + NT * 256;

    // ---- prep: convert feat_word to bf16 (1 item/thread); fold weights ----
    cvt_bf16<<<dim3(6400), 256, 0, stream>>>(feat_word, wfb, NW * 256 / 8);
    fold_kernel<<<dim3(64), 256, 0, stream>>>(Wk, bk, Wv, bv, rel_att, rel_msg,
                                              B_t1, B_w, B_t2, bias_t1, bias_w, bias_t2);
    TransP tp;
    tp.s[0] = Wq;            tp.d[0] = B_t1;   // Wq[topic]
    tp.s[1] = Wq + 131072;   tp.d[1] = Wq2t;   // Wq[doc]
    tp.s[2] = Whh;           tp.d[2] = Whht;
    tp.s[3] = Wih;           tp.d[3] = Wiht;
    tp.s[4] = Wa;            tp.d[4] = Wa0t;
    tp.s[5] = Wa + 65536;    tp.d[5] = Wa1t;
    wtrans6<<<dim3(256, 6), 256, 0, stream>>>(tp);
    copy_bias<<<dim3(1), 256, 0, stream>>>(bq, bias_t1);

    // ---- word GEMM: bf16-A gload_lds, unswapped big-tile, XCD swizzle ----
    gemm_w<false, unsigned char, 0, true, false><<<dim3(8, 200), 512, 0, stream>>>(
        wfb, B_w, bias_w, w8, NW, 1024, nullptr, nullptr, 0);

    // ---- merged phase-1 small GEMMs (q_t + kv1 + r2) ----
    gemm_qkv<<<dim3(8, 16), 256, 0, stream>>>(
        feat_topic, B_t1, bias_t1, q_t, kv1, NT, ht_prev, Whht, bhh, r2);
    gemm_w<true, short, 0, false, true><<<dim3(2, 79), 512, 0, stream>>>(
        feat_doc, Wq2t, bq + 512, qd, ND, 256, nullptr, nullptr, 0);

    // ---- messages into topic (tt:64/dst, wt:128/dst, both fp8) ----
    msg_k<64, 128><<<dim3(NT), 256, 0, stream>>>(
        q_t, 256,
        kv1, 512, 0, 256, src_tt,
        w8, 1024, 0, 256, src_wt,
        rel_pri, 0, 1, ttop, NT);

    // ---- topic update: mix -> RNN tanh -> LN ----
    gemm_lds<false, short, 1, false><<<dim3(2, 16), 256, 0, stream>>>(
        ttop, Wa0t, ba, mixb, NT, 256, feat_topic, skip, 0);
    gemm_lds<false, float, 2, false><<<dim3(2, 16), 256, 0, stream>>>(
        mixb, Wiht, bih, out_topic, NT, 256, r2, nullptr, 0);
    ln_k<true><<<dim3(500), 256, 0, stream>>>(out_topic, ln_g, ln_b, NT, xt2);

    // ---- phase-2 topic projections (fp8 out) ----
    gemm_lds<false, unsigned char, 0, false><<<dim3(4, 16), 256, 0, stream>>>(
        xt2, B_t2, bias_t2, kv2, NT, 512, nullptr, nullptr, 0);

    // ---- messages into doc (td:16/dst, wd:16/dst, both fp8) ----
    msg_k<16, 16><<<dim3(ND), 256, 0, stream>>>(
        qd, 256,
        kv2, 512, 0, 256, src_td,
        w8, 1024, 512, 768, src_wd,
        rel_pri, 2, 3, tdoc, ND);

    // ---- doc update: mix -> LN ----
    gemm_w<false, float, 1, false, true><<<dim3(2, 79), 512, 0, stream>>>(
        tdoc, Wa1t, ba + 256, out_doc, ND, 256, feat_doc, skip, 1);
    ln_k<false><<<dim3(5000), 256, 0, stream>>>(out_doc, ln_g + 256, ln_b + 256, ND, nullptr);
}